// Round 1
// baseline (1299.708 us; speedup 1.0000x reference)
//
#include <hip/hip_runtime.h>
#include <math.h>

#define NB 2
#define NN 576
#define NC 128
#define EPSV 1e-5f

__device__ __forceinline__ float geluf(float x) {
    return 0.5f * x * (1.0f + erff(x * 0.70710678118654752f));
}

// x (B,C,HW) -> tokens (B,HW,C)
__global__ void k_tok(const float* __restrict__ x, float* __restrict__ tok) {
    int b = blockIdx.y;
    int idx = blockIdx.x * 256 + threadIdx.x;
    if (idx < NN * NC) {
        int n = idx >> 7, c = idx & 127;
        tok[(size_t)b * NN * NC + idx] = x[((size_t)b * NC + c) * NN + n];
    }
}

// out[r, ooff+co] = sum_k A[r,k] * W[co*wstride + wo + k] + bias[co]
// blockDim.x = CO (<=384), 8 rows per block, K=128 fixed.
__global__ void k_gemm(const float* __restrict__ A, const float* __restrict__ W,
                       int wstride, int wo, const float* __restrict__ bias,
                       float* __restrict__ out, int ostride, int ooff) {
    const int CO = blockDim.x;
    const int t = threadIdx.x;
    const int r0 = blockIdx.x * 8;
    __shared__ float a_s[8][128];
    __shared__ float w_s[384 * 33];

    for (int idx = t; idx < 8 * 128; idx += CO) {
        a_s[idx >> 7][idx & 127] = A[(size_t)(r0 + (idx >> 7)) * 128 + (idx & 127)];
    }
    float acc[8] = {0.f,0.f,0.f,0.f,0.f,0.f,0.f,0.f};
    for (int k0 = 0; k0 < 128; k0 += 32) {
        __syncthreads();
        for (int it = 0; it < 32; ++it) {
            int idx = t + it * CO;
            int co = idx >> 5, kk = idx & 31;
            w_s[co * 33 + kk] = W[(size_t)co * wstride + wo + k0 + kk];
        }
        __syncthreads();
        const float* wrow = &w_s[t * 33];
        #pragma unroll
        for (int kq = 0; kq < 8; ++kq) {
            float w0 = wrow[kq*4+0], w1 = wrow[kq*4+1], w2 = wrow[kq*4+2], w3 = wrow[kq*4+3];
            #pragma unroll
            for (int r = 0; r < 8; ++r) {
                const float4 av = *reinterpret_cast<const float4*>(&a_s[r][k0 + kq*4]);
                acc[r] += av.x*w0 + av.y*w1 + av.z*w2 + av.w*w3;
            }
        }
    }
    float bv = bias ? bias[t] : 0.0f;
    #pragma unroll
    for (int r = 0; r < 8; ++r) {
        out[(size_t)(r0 + r) * ostride + ooff + t] = acc[r] + bv;
    }
}

// Fused MHA per (b,i): scores+softmax+AV+out-proj+residual+LN(n1)
__global__ __launch_bounds__(256) void k_mha(
    const float* __restrict__ tok, const float* __restrict__ qkv,
    const float* __restrict__ ow, const float* __restrict__ ob,
    const float* __restrict__ nw, const float* __restrict__ nb,
    float* __restrict__ attn)
{
    const int bi = blockIdx.x;
    const int b = bi / NN, i = bi - b * NN;
    const int t = threadIdx.x;
    const int jl = t & 63, q = t >> 6;

    __shared__ float q_s[128];
    __shared__ float k_s[64][129];
    __shared__ float s_s[576][8];
    __shared__ float inv_s[8];
    __shared__ float aggp[2][128];
    __shared__ float agg_s[128];
    __shared__ float red1[4], red2[4];

    const size_t rowb = (size_t)(b * NN + i) * 384;
    if (t < 128) q_s[t] = qkv[rowb + t] * 0.25f;

    for (int tile = 0; tile < 9; ++tile) {
        const int j0 = tile * 64;
        __syncthreads();
        for (int idx = t; idx < 64 * 128; idx += 256) {
            int r = idx >> 7, cc = idx & 127;
            k_s[r][cc] = qkv[(size_t)(b * NN + j0 + r) * 384 + 128 + cc];
        }
        __syncthreads();
        #pragma unroll
        for (int hh = 0; hh < 2; ++hh) {
            int h = q * 2 + hh;
            float s = 0.f;
            #pragma unroll
            for (int d = 0; d < 16; ++d) s += q_s[h*16+d] * k_s[jl][h*16+d];
            s_s[j0 + jl][h] = s;
        }
    }
    __syncthreads();
    #pragma unroll
    for (int hh = 0; hh < 2; ++hh) {
        int h = q * 2 + hh;
        float mx = -1e30f;
        for (int j = jl; j < NN; j += 64) mx = fmaxf(mx, s_s[j][h]);
        #pragma unroll
        for (int off = 32; off > 0; off >>= 1) mx = fmaxf(mx, __shfl_xor(mx, off));
        float sm = 0.f;
        for (int j = jl; j < NN; j += 64) {
            float e = __expf(s_s[j][h] - mx);
            s_s[j][h] = e;
            sm += e;
        }
        #pragma unroll
        for (int off = 32; off > 0; off >>= 1) sm += __shfl_xor(sm, off);
        if (jl == 0) inv_s[h] = 1.0f / sm;
    }
    __syncthreads();
    {
        const int c = t & 127, half = t >> 7;
        const int h = c >> 4;
        float acc = 0.f;
        for (int j = half; j < NN; j += 2)
            acc += s_s[j][h] * qkv[(size_t)(b * NN + j) * 384 + 256 + c];
        aggp[half][c] = acc;
    }
    __syncthreads();
    if (t < 128) agg_s[t] = (aggp[0][t] + aggp[1][t]) * inv_s[t >> 4];
    __syncthreads();
    float val = 0.f;
    if (t < 128) {
        float o = ob[t];
        const float4* wrow = reinterpret_cast<const float4*>(ow + (size_t)t * 128);
        const float4* ar = reinterpret_cast<const float4*>(agg_s);
        #pragma unroll 8
        for (int kq = 0; kq < 32; ++kq) {
            float4 w = wrow[kq], a = ar[kq];
            o += w.x*a.x + w.y*a.y + w.z*a.z + w.w*a.w;
        }
        val = o + tok[(size_t)(b * NN + i) * 128 + t];
    }
    float s1 = val, s2 = val * val;
    #pragma unroll
    for (int off = 32; off > 0; off >>= 1) {
        s1 += __shfl_xor(s1, off);
        s2 += __shfl_xor(s2, off);
    }
    if (jl == 0) { red1[q] = s1; red2[q] = s2; }
    __syncthreads();
    float tot1 = red1[0]+red1[1]+red1[2]+red1[3];
    float tot2 = red2[0]+red2[1]+red2[2]+red2[3];
    float mean = tot1 * (1.0f/128.0f);
    float var  = tot2 * (1.0f/128.0f) - mean*mean;
    float rstd = rsqrtf(var + EPSV);
    if (t < 128) {
        attn[(size_t)(b * NN + i) * 128 + t] = (val - mean) * rstd * nw[t] + nb[t];
    }
}

// Fused GCN per (b,i): edge MLP (LN+gelu+e2) over all j, softmax_j, adj*v,
// o-proj + residual + LN.  abv row = [xa(128) | xb(128) | v(128)].
__global__ __launch_bounds__(256) void k_gcn_edge(
    const float* __restrict__ xin, const float* __restrict__ abv,
    const float* __restrict__ e1b, const float* __restrict__ elnw, const float* __restrict__ elnb,
    const float* __restrict__ e2w, const float* __restrict__ e2b,
    const float* __restrict__ ow, const float* __restrict__ ob,
    const float* __restrict__ nw, const float* __restrict__ nb,
    float* __restrict__ gout)
{
    const int bi = blockIdx.x;
    const int b = bi / NN, i = bi - b * NN;
    const int t = threadIdx.x;
    const int jl = t & 63, q = t >> 6;

    __shared__ float xa_s[128], e1b_s[128], elnw_s[128], elnb_s[128];
    __shared__ float e2w_s[4][128];
    __shared__ float xb_s[64][129];
    __shared__ float part1[4][64], part2[4][64];
    __shared__ float pp[4][4][64];
    __shared__ float ew_s[576][4];
    __shared__ float inv_s[4];
    __shared__ float aggp[2][128];
    __shared__ float agg_s[128];
    __shared__ float red1[4], red2[4];

    const size_t rowb = (size_t)(b * NN + i) * 384;
    if (t < 128) {
        xa_s[t]   = abv[rowb + t];
        e1b_s[t]  = e1b[t];
        elnw_s[t] = elnw[t];
        elnb_s[t] = elnb[t];
    }
    for (int idx = t; idx < 512; idx += 256) (&e2w_s[0][0])[idx] = e2w[idx];

    const int c0 = q * 32;
    for (int tile = 0; tile < 9; ++tile) {
        const int j0 = tile * 64;
        __syncthreads();
        for (int idx = t; idx < 64 * 128; idx += 256) {
            int r = idx >> 7, cc = idx & 127;
            xb_s[r][cc] = abv[(size_t)(b * NN + j0 + r) * 384 + 128 + cc];
        }
        __syncthreads();
        float s1 = 0.f, s2 = 0.f;
        #pragma unroll
        for (int cc = 0; cc < 32; ++cc) {
            int c = c0 + cc;
            float e = xa_s[c] + xb_s[jl][c] + e1b_s[c];
            s1 += e; s2 += e * e;
        }
        part1[q][jl] = s1; part2[q][jl] = s2;
        __syncthreads();
        float sum = part1[0][jl] + part1[1][jl] + part1[2][jl] + part1[3][jl];
        float sq  = part2[0][jl] + part2[1][jl] + part2[2][jl] + part2[3][jl];
        float mean = sum * (1.0f/128.0f);
        float var  = sq * (1.0f/128.0f) - mean * mean;
        float rstd = rsqrtf(var + EPSV);
        float p0 = 0.f, p1 = 0.f, p2 = 0.f, p3 = 0.f;
        #pragma unroll 8
        for (int cc = 0; cc < 32; ++cc) {
            int c = c0 + cc;
            float e = xa_s[c] + xb_s[jl][c] + e1b_s[c];
            float nrm = (e - mean) * rstd * elnw_s[c] + elnb_s[c];
            float g = geluf(nrm);
            p0 += g * e2w_s[0][c];
            p1 += g * e2w_s[1][c];
            p2 += g * e2w_s[2][c];
            p3 += g * e2w_s[3][c];
        }
        pp[q][0][jl] = p0; pp[q][1][jl] = p1; pp[q][2][jl] = p2; pp[q][3][jl] = p3;
        __syncthreads();
        if (q == 0) {
            #pragma unroll
            for (int h = 0; h < 4; ++h) {
                ew_s[j0 + jl][h] = pp[0][h][jl] + pp[1][h][jl] + pp[2][h][jl] + pp[3][h][jl] + e2b[h];
            }
        }
    }
    __syncthreads();
    // softmax over j for head h = q
    {
        float mx = -1e30f;
        for (int j = jl; j < NN; j += 64) mx = fmaxf(mx, ew_s[j][q]);
        #pragma unroll
        for (int off = 32; off > 0; off >>= 1) mx = fmaxf(mx, __shfl_xor(mx, off));
        float sm = 0.f;
        for (int j = jl; j < NN; j += 64) {
            float e = __expf(ew_s[j][q] - mx);
            ew_s[j][q] = e;
            sm += e;
        }
        #pragma unroll
        for (int off = 32; off > 0; off >>= 1) sm += __shfl_xor(sm, off);
        if (jl == 0) inv_s[q] = 1.0f / sm;
    }
    __syncthreads();
    {
        const int c = t & 127, half = t >> 7;
        const int h = c >> 5;
        float acc = 0.f;
        for (int j = half; j < NN; j += 2)
            acc += ew_s[j][h] * abv[(size_t)(b * NN + j) * 384 + 256 + c];
        aggp[half][c] = acc;
    }
    __syncthreads();
    if (t < 128) agg_s[t] = (aggp[0][t] + aggp[1][t]) * inv_s[t >> 5];
    __syncthreads();
    float val = 0.f;
    if (t < 128) {
        float o = ob[t];
        const float4* wrow = reinterpret_cast<const float4*>(ow + (size_t)t * 128);
        const float4* ar = reinterpret_cast<const float4*>(agg_s);
        #pragma unroll 8
        for (int kq = 0; kq < 32; ++kq) {
            float4 w = wrow[kq], a = ar[kq];
            o += w.x*a.x + w.y*a.y + w.z*a.z + w.w*a.w;
        }
        val = o + xin[(size_t)(b * NN + i) * 128 + t];
    }
    float s1 = val, s2 = val * val;
    #pragma unroll
    for (int off = 32; off > 0; off >>= 1) {
        s1 += __shfl_xor(s1, off);
        s2 += __shfl_xor(s2, off);
    }
    if (jl == 0) { red1[q] = s1; red2[q] = s2; }
    __syncthreads();
    float tot1 = red1[0]+red1[1]+red1[2]+red1[3];
    float tot2 = red2[0]+red2[1]+red2[2]+red2[3];
    float mean = tot1 * (1.0f/128.0f);
    float var  = tot2 * (1.0f/128.0f) - mean*mean;
    float rstd = rsqrtf(var + EPSV);
    if (t < 128) {
        gout[(size_t)(b * NN + i) * 128 + t] = (val - mean) * rstd * nw[t] + nb[t];
    }
}

// Final: LN(n2) on g, concat(attn, g), f1 + LN(fln) + gelu + f2, + tokens,
// write out in (B,C,H,W) layout.  block = 128 threads.
__global__ __launch_bounds__(128) void k_final(
    const float* __restrict__ tok, const float* __restrict__ attn, const float* __restrict__ g,
    const float* __restrict__ n2w, const float* __restrict__ n2b,
    const float* __restrict__ f1w, const float* __restrict__ f1b,
    const float* __restrict__ flnw, const float* __restrict__ flnb,
    const float* __restrict__ f2w, const float* __restrict__ f2b,
    float* __restrict__ out)
{
    const int bi = blockIdx.x;
    const int b = bi / NN, i = bi - b * NN;
    const int t = threadIdx.x;  // 128
    __shared__ float cat_s[256];
    __shared__ float gl_s[128];
    __shared__ float red1[2], red2[2];

    const size_t row = (size_t)(b * NN + i) * 128;
    cat_s[t] = attn[row + t];
    float gv = g[row + t];
    // LN(n2)
    {
        float s1 = gv, s2 = gv * gv;
        #pragma unroll
        for (int off = 32; off > 0; off >>= 1) { s1 += __shfl_xor(s1, off); s2 += __shfl_xor(s2, off); }
        if ((t & 63) == 0) { red1[t >> 6] = s1; red2[t >> 6] = s2; }
        __syncthreads();
        float mean = (red1[0] + red1[1]) * (1.0f/128.0f);
        float var  = (red2[0] + red2[1]) * (1.0f/128.0f) - mean*mean;
        float rstd = rsqrtf(var + EPSV);
        cat_s[128 + t] = (gv - mean) * rstd * n2w[t] + n2b[t];
    }
    __syncthreads();
    // f1: dot over 256
    float f = f1b[t];
    {
        const float4* wr = reinterpret_cast<const float4*>(f1w + (size_t)t * 256);
        const float4* cr = reinterpret_cast<const float4*>(cat_s);
        #pragma unroll 8
        for (int kq = 0; kq < 64; ++kq) {
            float4 w = wr[kq], c = cr[kq];
            f += w.x*c.x + w.y*c.y + w.z*c.z + w.w*c.w;
        }
    }
    // LN(fln) + gelu
    {
        float s1 = f, s2 = f * f;
        #pragma unroll
        for (int off = 32; off > 0; off >>= 1) { s1 += __shfl_xor(s1, off); s2 += __shfl_xor(s2, off); }
        __syncthreads();   // protect red reuse
        if ((t & 63) == 0) { red1[t >> 6] = s1; red2[t >> 6] = s2; }
        __syncthreads();
        float mean = (red1[0] + red1[1]) * (1.0f/128.0f);
        float var  = (red2[0] + red2[1]) * (1.0f/128.0f) - mean*mean;
        float rstd = rsqrtf(var + EPSV);
        float nrm = (f - mean) * rstd * flnw[t] + flnb[t];
        gl_s[t] = geluf(nrm);
    }
    __syncthreads();
    float o = f2b[t];
    {
        const float4* wr = reinterpret_cast<const float4*>(f2w + (size_t)t * 128);
        const float4* gr = reinterpret_cast<const float4*>(gl_s);
        #pragma unroll 8
        for (int kq = 0; kq < 32; ++kq) {
            float4 w = wr[kq], gg = gr[kq];
            o += w.x*gg.x + w.y*gg.y + w.z*gg.z + w.w*gg.w;
        }
    }
    out[((size_t)b * 128 + t) * 576 + i] = tok[row + t] + o;
}

extern "C" void kernel_launch(void* const* d_in, const int* in_sizes, int n_in,
                              void* d_out, int out_size, void* d_ws, size_t ws_size,
                              hipStream_t stream) {
    const float* x         = (const float*)d_in[0];
    const float* mha_in_w  = (const float*)d_in[1];
    const float* mha_in_b  = (const float*)d_in[2];
    const float* mha_out_w = (const float*)d_in[3];
    const float* mha_out_b = (const float*)d_in[4];
    const float* gv_w[2]  = {(const float*)d_in[5],  (const float*)d_in[17]};
    const float* gv_b[2]  = {(const float*)d_in[6],  (const float*)d_in[18]};
    const float* ge1_w[2] = {(const float*)d_in[7],  (const float*)d_in[19]};
    const float* ge1_b[2] = {(const float*)d_in[8],  (const float*)d_in[20]};
    const float* geln_w[2]= {(const float*)d_in[9],  (const float*)d_in[21]};
    const float* geln_b[2]= {(const float*)d_in[10], (const float*)d_in[22]};
    const float* ge2_w[2] = {(const float*)d_in[11], (const float*)d_in[23]};
    const float* ge2_b[2] = {(const float*)d_in[12], (const float*)d_in[24]};
    const float* go_w[2]  = {(const float*)d_in[13], (const float*)d_in[25]};
    const float* go_b[2]  = {(const float*)d_in[14], (const float*)d_in[26]};
    const float* gn_w[2]  = {(const float*)d_in[15], (const float*)d_in[27]};
    const float* gn_b[2]  = {(const float*)d_in[16], (const float*)d_in[28]};
    const float* n1w = (const float*)d_in[29];
    const float* n1b = (const float*)d_in[30];
    const float* n2w = (const float*)d_in[31];
    const float* n2b = (const float*)d_in[32];
    const float* f1w = (const float*)d_in[33];
    const float* f1b = (const float*)d_in[34];
    const float* flnw = (const float*)d_in[35];
    const float* flnb = (const float*)d_in[36];
    const float* f2w = (const float*)d_in[37];
    const float* f2b = (const float*)d_in[38];

    float* ws     = (float*)d_ws;
    float* tokens = ws;                   // 147456
    float* attn   = ws + 147456;          // 147456
    float* g      = ws + 2 * 147456;      // 147456
    float* abv    = ws + 3 * 147456;      // 442368

    k_tok<<<dim3(288, 2), 256, 0, stream>>>(x, tokens);
    // qkv = tokens @ mha_in_w^T + b  -> abv (stride 384)
    k_gemm<<<144, 384, 0, stream>>>(tokens, mha_in_w, 128, 0, mha_in_b, abv, 384, 0);
    k_mha<<<1152, 256, 0, stream>>>(tokens, abv, mha_out_w, mha_out_b, n1w, n1b, attn);

    for (int l = 0; l < 2; ++l) {
        const float* xin = (l == 0) ? attn : g;
        // xa | xb | v
        k_gemm<<<144, 128, 0, stream>>>(xin, ge1_w[l], 256, 0,   nullptr,  abv, 384, 0);
        k_gemm<<<144, 128, 0, stream>>>(xin, ge1_w[l], 256, 128, nullptr,  abv, 384, 128);
        k_gemm<<<144, 128, 0, stream>>>(xin, gv_w[l],  128, 0,   gv_b[l],  abv, 384, 256);
        k_gcn_edge<<<1152, 256, 0, stream>>>(xin, abv,
            ge1_b[l], geln_w[l], geln_b[l], ge2_w[l], ge2_b[l],
            go_w[l], go_b[l], gn_w[l], gn_b[l], g);
    }
    k_final<<<1152, 128, 0, stream>>>(tokens, attn, g, n2w, n2b,
        f1w, f1b, flnw, flnb, f2w, f2b, (float*)d_out);
}

// Round 2
// 608.523 us; speedup vs baseline: 2.1358x; 2.1358x over previous
//
#include <hip/hip_runtime.h>
#include <hip/hip_fp16.h>
#include <math.h>

#define NN 576
#define EPSV 1e-5f

__device__ __forceinline__ float geluf(float x) {
    return 0.5f * x * (1.0f + erff(x * 0.70710678118654752f));
}

// x (B,C,HW) -> tokens (B,HW,C)
__global__ void k_tok(const float* __restrict__ x, float* __restrict__ tok) {
    int b = blockIdx.y;
    int idx = blockIdx.x * 256 + threadIdx.x;
    if (idx < NN * 128) {
        int n = idx >> 7, c = idx & 127;
        tok[(size_t)b * NN * 128 + idx] = x[((size_t)b * 128 + c) * NN + n];
    }
}

// wT[k*384+o] = mha_in_w[o*128+k]   (49152 elems)
__global__ void k_wtrq(const float* __restrict__ w, float* __restrict__ dst) {
    int idx = blockIdx.x * 256 + threadIdx.x;
    int k = idx / 384, o = idx - k * 384;
    dst[idx] = w[o * 128 + k];
}

// combined layer weight: cols 0..127 = w1a, 128..255 = w1b, 256..383 = v_w
__global__ void k_wtr(const float* __restrict__ e1w, const float* __restrict__ vw,
                      float* __restrict__ dst) {
    int idx = blockIdx.x * 256 + threadIdx.x;
    int k = idx / 384, o = idx - k * 384;
    float v;
    if (o < 128)      v = e1w[o * 256 + k];
    else if (o < 256) v = e1w[(o - 128) * 256 + 128 + k];
    else              v = vw[(o - 256) * 128 + k];
    dst[idx] = v;
}

// out[r, o] = sum_k A[r,k]*wT[k*384+o] (+bias chunk), 4 rows/block, 384 threads
__global__ __launch_bounds__(384) void k_gemmT(
    const float* __restrict__ A, const float* __restrict__ wT,
    const float* __restrict__ b0, const float* __restrict__ b1, const float* __restrict__ b2,
    float* __restrict__ out)
{
    const int t = threadIdx.x;
    const int r0 = blockIdx.x * 4;
    __shared__ float a_s[4][132];
    if (t < 128) {
        float4 v = *(const float4*)(A + (size_t)(r0 + (t >> 5)) * 128 + (t & 31) * 4);
        *(float4*)&a_s[t >> 5][(t & 31) * 4] = v;
    }
    __syncthreads();
    float acc0 = 0.f, acc1 = 0.f, acc2 = 0.f, acc3 = 0.f;
    #pragma unroll 8
    for (int k = 0; k < 128; ++k) {
        float w = wT[(size_t)k * 384 + t];
        acc0 += a_s[0][k] * w;
        acc1 += a_s[1][k] * w;
        acc2 += a_s[2][k] * w;
        acc3 += a_s[3][k] * w;
    }
    const float* bp = (t < 128) ? b0 : ((t < 256) ? b1 : b2);
    float bv = bp ? bp[t & 127] : 0.f;
    out[(size_t)(r0 + 0) * 384 + t] = acc0 + bv;
    out[(size_t)(r0 + 1) * 384 + t] = acc1 + bv;
    out[(size_t)(r0 + 2) * 384 + t] = acc2 + bv;
    out[(size_t)(r0 + 3) * 384 + t] = acc3 + bv;
}

// kT[(b*128+hd)*576 + j] = qkv[(b*576+j)*384 + 128 + hd]
__global__ void k_ktr(const float* __restrict__ qkv, float* __restrict__ kT) {
    int idx = blockIdx.x * 256 + threadIdx.x;   // 147456
    int j = idx % NN; int rest = idx / NN;
    int hd = rest & 127, b = rest >> 7;
    kT[idx] = qkv[(size_t)(b * NN + j) * 384 + 128 + hd];
}

// in-place row centering: row -= mean(row (+bias));  1 wave per row, stride 384
__global__ __launch_bounds__(256) void k_center(float* __restrict__ buf, int off,
                                                const float* __restrict__ bias) {
    int row = blockIdx.x * 4 + (threadIdx.x >> 6);
    int lane = threadIdx.x & 63;
    float* p = buf + (size_t)row * 384 + off + lane * 2;
    float2 v = *(float2*)p;
    if (bias) { v.x += bias[lane * 2]; v.y += bias[lane * 2 + 1]; }
    float s = v.x + v.y;
    #pragma unroll
    for (int o = 32; o > 0; o >>= 1) s += __shfl_xor(s, o);
    float m = s * (1.0f / 128.0f);
    float2 r; r.x = v.x - m; r.y = v.y - m;
    *(float2*)p = r;
}

// Edge MLP: one thread per (i,j) pair, 16x16 tile per block. No reductions.
// abv rows: [ua(128,centered) | wb(128,centered incl e1b) | v(128)]
__global__ __launch_bounds__(256) void k_edge(
    const float* __restrict__ abv,
    const float* __restrict__ elnw, const float* __restrict__ elnb,
    const float* __restrict__ e2w, const float* __restrict__ e2b,
    __half* __restrict__ ew)
{
    const int jt = blockIdx.x, it = blockIdx.y, b = blockIdx.z;
    const int i0 = it * 16, j0 = jt * 16;
    const int t = threadIdx.x;
    __shared__ float ua_s[16][132], wb_s[16][132];

    for (int idx = t; idx < 512; idx += 256) {
        int r = idx >> 5, cq = idx & 31;
        *(float4*)&ua_s[r][cq * 4] = *(const float4*)(abv + (size_t)(b * NN + i0 + r) * 384 + cq * 4);
        *(float4*)&wb_s[r][cq * 4] = *(const float4*)(abv + (size_t)(b * NN + j0 + r) * 384 + 128 + cq * 4);
    }
    __syncthreads();

    const int ti = t >> 4, tj = t & 15;
    const float4* uar = (const float4*)ua_s[ti];
    const float4* wbr = (const float4*)wb_s[tj];

    float s2 = 0.f;
    #pragma unroll
    for (int cq = 0; cq < 32; ++cq) {
        float4 u = uar[cq], w = wbr[cq];
        float e0 = u.x + w.x, e1 = u.y + w.y, e2v = u.z + w.z, e3 = u.w + w.w;
        s2 += e0 * e0 + e1 * e1 + e2v * e2v + e3 * e3;
    }
    float rstd = rsqrtf(s2 * (1.0f / 128.0f) + EPSV);

    float p0 = 0.f, p1 = 0.f, p2 = 0.f, p3 = 0.f;
    #pragma unroll 4
    for (int cq = 0; cq < 32; ++cq) {
        float4 u = uar[cq], w = wbr[cq];
        float4 lw = ((const float4*)elnw)[cq];
        float4 lb = ((const float4*)elnb)[cq];
        float4 q0 = ((const float4*)(e2w))[cq];
        float4 q1 = ((const float4*)(e2w + 128))[cq];
        float4 q2 = ((const float4*)(e2w + 256))[cq];
        float4 q3 = ((const float4*)(e2w + 384))[cq];
        float g;
        g = geluf((u.x + w.x) * rstd * lw.x + lb.x); p0 += g * q0.x; p1 += g * q1.x; p2 += g * q2.x; p3 += g * q3.x;
        g = geluf((u.y + w.y) * rstd * lw.y + lb.y); p0 += g * q0.y; p1 += g * q1.y; p2 += g * q2.y; p3 += g * q3.y;
        g = geluf((u.z + w.z) * rstd * lw.z + lb.z); p0 += g * q0.z; p1 += g * q1.z; p2 += g * q2.z; p3 += g * q3.z;
        g = geluf((u.w + w.w) * rstd * lw.w + lb.w); p0 += g * q0.w; p1 += g * q1.w; p2 += g * q2.w; p3 += g * q3.w;
    }
    __half2 h01 = __floats2half2_rn(p0 + e2b[0], p1 + e2b[1]);
    __half2 h23 = __floats2half2_rn(p2 + e2b[2], p3 + e2b[3]);
    __half* dst = ew + ((size_t)(b * NN + i0 + ti) * NN + j0 + tj) * 4;
    *(__half2*)dst = h01;
    *(__half2*)(dst + 2) = h23;
}

// per (b,i): softmax over j per head + AV + o-proj + residual + LN
__global__ __launch_bounds__(256) void k_gcn_agg(
    const float* __restrict__ xin, const float* __restrict__ abv,
    const __half* __restrict__ ew,
    const float* __restrict__ ow, const float* __restrict__ ob,
    const float* __restrict__ nw, const float* __restrict__ nb,
    float* __restrict__ gout)
{
    const int bi = blockIdx.x;
    const int b = bi / NN, i = bi - b * NN;
    const int t = threadIdx.x;
    const int jl = t & 63, q = t >> 6;

    __shared__ float ew_s[576][5];
    __shared__ float inv_s[4];
    __shared__ float aggp[2][128];
    __shared__ float agg_s[128];
    __shared__ float red1[4], red2[4];

    const __half* ewb = ew + (size_t)(b * NN + i) * NN * 4;
    for (int j = t; j < NN; j += 256) {
        uint2 raw = *(const uint2*)(ewb + j * 4);
        __half2 h01 = *(__half2*)&raw.x;
        __half2 h23 = *(__half2*)&raw.y;
        ew_s[j][0] = __low2float(h01);
        ew_s[j][1] = __high2float(h01);
        ew_s[j][2] = __low2float(h23);
        ew_s[j][3] = __high2float(h23);
    }
    __syncthreads();
    {
        float mx = -1e30f;
        for (int j = jl; j < NN; j += 64) mx = fmaxf(mx, ew_s[j][q]);
        #pragma unroll
        for (int off = 32; off > 0; off >>= 1) mx = fmaxf(mx, __shfl_xor(mx, off));
        float sm = 0.f;
        for (int j = jl; j < NN; j += 64) {
            float e = __expf(ew_s[j][q] - mx);
            ew_s[j][q] = e;
            sm += e;
        }
        #pragma unroll
        for (int off = 32; off > 0; off >>= 1) sm += __shfl_xor(sm, off);
        if (jl == 0) inv_s[q] = 1.0f / sm;
    }
    __syncthreads();
    {
        const int c = t & 127, half = t >> 7;
        const int h = c >> 5;
        float acc = 0.f;
        for (int j = half; j < NN; j += 2)
            acc += ew_s[j][h] * abv[(size_t)(b * NN + j) * 384 + 256 + c];
        aggp[half][c] = acc;
    }
    __syncthreads();
    if (t < 128) agg_s[t] = (aggp[0][t] + aggp[1][t]) * inv_s[t >> 5];
    __syncthreads();
    float val = 0.f;
    if (t < 128) {
        float o = ob[t];
        const float4* wrow = reinterpret_cast<const float4*>(ow + (size_t)t * 128);
        const float4* ar = reinterpret_cast<const float4*>(agg_s);
        #pragma unroll 8
        for (int kq = 0; kq < 32; ++kq) {
            float4 w = wrow[kq], a = ar[kq];
            o += w.x * a.x + w.y * a.y + w.z * a.z + w.w * a.w;
        }
        val = o + xin[(size_t)(b * NN + i) * 128 + t];
    }
    float s1 = val, s2 = val * val;
    #pragma unroll
    for (int off = 32; off > 0; off >>= 1) {
        s1 += __shfl_xor(s1, off);
        s2 += __shfl_xor(s2, off);
    }
    if (jl == 0) { red1[q] = s1; red2[q] = s2; }
    __syncthreads();
    float tot1 = red1[0] + red1[1] + red1[2] + red1[3];
    float tot2 = red2[0] + red2[1] + red2[2] + red2[3];
    float mean = tot1 * (1.0f / 128.0f);
    float var = tot2 * (1.0f / 128.0f) - mean * mean;
    float rstd = rsqrtf(var + EPSV);
    if (t < 128) {
        gout[(size_t)(b * NN + i) * 128 + t] = (val - mean) * rstd * nw[t] + nb[t];
    }
}

// MHA per (b,i): coalesced scores via kT + softmax + AV + o-proj + residual + LN
__global__ __launch_bounds__(256) void k_mha2(
    const float* __restrict__ tok, const float* __restrict__ qkv,
    const float* __restrict__ kT,
    const float* __restrict__ ow, const float* __restrict__ ob,
    const float* __restrict__ nw, const float* __restrict__ nb,
    float* __restrict__ attn)
{
    const int bi = blockIdx.x;
    const int b = bi / NN, i = bi - b * NN;
    const int t = threadIdx.x;
    const int jl = t & 63, q = t >> 6;

    __shared__ float q_s[128];
    __shared__ float s_s[576][9];
    __shared__ float inv_s[8];
    __shared__ float aggp[2][128];
    __shared__ float agg_s[128];
    __shared__ float red1[4], red2[4];

    if (t < 128) q_s[t] = qkv[(size_t)(b * NN + i) * 384 + t] * 0.25f;
    __syncthreads();

    const float* kb = kT + (size_t)b * 128 * NN;
    for (int j = t; j < NN; j += 256) {
        float accs[8] = {0.f,0.f,0.f,0.f,0.f,0.f,0.f,0.f};
        const float* kc = kb + j;
        #pragma unroll
        for (int hq = 0; hq < 32; ++hq) {
            float4 qv = ((const float4*)q_s)[hq];
            accs[(hq * 4 + 0) >> 4] += qv.x * kc[(hq * 4 + 0) * NN];
            accs[(hq * 4 + 1) >> 4] += qv.y * kc[(hq * 4 + 1) * NN];
            accs[(hq * 4 + 2) >> 4] += qv.z * kc[(hq * 4 + 2) * NN];
            accs[(hq * 4 + 3) >> 4] += qv.w * kc[(hq * 4 + 3) * NN];
        }
        #pragma unroll
        for (int h = 0; h < 8; ++h) s_s[j][h] = accs[h];
    }
    __syncthreads();
    #pragma unroll
    for (int hh = 0; hh < 2; ++hh) {
        int h = q * 2 + hh;
        float mx = -1e30f;
        for (int j = jl; j < NN; j += 64) mx = fmaxf(mx, s_s[j][h]);
        #pragma unroll
        for (int off = 32; off > 0; off >>= 1) mx = fmaxf(mx, __shfl_xor(mx, off));
        float sm = 0.f;
        for (int j = jl; j < NN; j += 64) {
            float e = __expf(s_s[j][h] - mx);
            s_s[j][h] = e;
            sm += e;
        }
        #pragma unroll
        for (int off = 32; off > 0; off >>= 1) sm += __shfl_xor(sm, off);
        if (jl == 0) inv_s[h] = 1.0f / sm;
    }
    __syncthreads();
    {
        const int c = t & 127, half = t >> 7;
        const int h = c >> 4;
        float acc = 0.f;
        for (int j = half; j < NN; j += 2)
            acc += s_s[j][h] * qkv[(size_t)(b * NN + j) * 384 + 256 + c];
        aggp[half][c] = acc;
    }
    __syncthreads();
    if (t < 128) agg_s[t] = (aggp[0][t] + aggp[1][t]) * inv_s[t >> 4];
    __syncthreads();
    float val = 0.f;
    if (t < 128) {
        float o = ob[t];
        const float4* wrow = reinterpret_cast<const float4*>(ow + (size_t)t * 128);
        const float4* ar = reinterpret_cast<const float4*>(agg_s);
        #pragma unroll 8
        for (int kq = 0; kq < 32; ++kq) {
            float4 w = wrow[kq], a = ar[kq];
            o += w.x * a.x + w.y * a.y + w.z * a.z + w.w * a.w;
        }
        val = o + tok[(size_t)(b * NN + i) * 128 + t];
    }
    float s1 = val, s2 = val * val;
    #pragma unroll
    for (int off = 32; off > 0; off >>= 1) {
        s1 += __shfl_xor(s1, off);
        s2 += __shfl_xor(s2, off);
    }
    if (jl == 0) { red1[q] = s1; red2[q] = s2; }
    __syncthreads();
    float tot1 = red1[0] + red1[1] + red1[2] + red1[3];
    float tot2 = red2[0] + red2[1] + red2[2] + red2[3];
    float mean = tot1 * (1.0f / 128.0f);
    float var = tot2 * (1.0f / 128.0f) - mean * mean;
    float rstd = rsqrtf(var + EPSV);
    if (t < 128) {
        attn[(size_t)(b * NN + i) * 128 + t] = (val - mean) * rstd * nw[t] + nb[t];
    }
}

// Final: LN(n2) on g, concat, f1 + LN + gelu + f2, + tokens, write (B,C,H,W)
__global__ __launch_bounds__(128) void k_final(
    const float* __restrict__ tok, const float* __restrict__ attn, const float* __restrict__ g,
    const float* __restrict__ n2w, const float* __restrict__ n2b,
    const float* __restrict__ f1w, const float* __restrict__ f1b,
    const float* __restrict__ flnw, const float* __restrict__ flnb,
    const float* __restrict__ f2w, const float* __restrict__ f2b,
    float* __restrict__ out)
{
    const int bi = blockIdx.x;
    const int b = bi / NN, i = bi - b * NN;
    const int t = threadIdx.x;
    __shared__ float cat_s[256];
    __shared__ float gl_s[128];
    __shared__ float red1[2], red2[2];

    const size_t row = (size_t)(b * NN + i) * 128;
    cat_s[t] = attn[row + t];
    float gv = g[row + t];
    {
        float s1 = gv, s2 = gv * gv;
        #pragma unroll
        for (int off = 32; off > 0; off >>= 1) { s1 += __shfl_xor(s1, off); s2 += __shfl_xor(s2, off); }
        if ((t & 63) == 0) { red1[t >> 6] = s1; red2[t >> 6] = s2; }
        __syncthreads();
        float mean = (red1[0] + red1[1]) * (1.0f / 128.0f);
        float var = (red2[0] + red2[1]) * (1.0f / 128.0f) - mean * mean;
        float rstd = rsqrtf(var + EPSV);
        cat_s[128 + t] = (gv - mean) * rstd * n2w[t] + n2b[t];
    }
    __syncthreads();
    float f = f1b[t];
    {
        const float4* wr = reinterpret_cast<const float4*>(f1w + (size_t)t * 256);
        const float4* cr = reinterpret_cast<const float4*>(cat_s);
        #pragma unroll 8
        for (int kq = 0; kq < 64; ++kq) {
            float4 w = wr[kq], c = cr[kq];
            f += w.x * c.x + w.y * c.y + w.z * c.z + w.w * c.w;
        }
    }
    {
        float s1 = f, s2 = f * f;
        #pragma unroll
        for (int off = 32; off > 0; off >>= 1) { s1 += __shfl_xor(s1, off); s2 += __shfl_xor(s2, off); }
        __syncthreads();
        if ((t & 63) == 0) { red1[t >> 6] = s1; red2[t >> 6] = s2; }
        __syncthreads();
        float mean = (red1[0] + red1[1]) * (1.0f / 128.0f);
        float var = (red2[0] + red2[1]) * (1.0f / 128.0f) - mean * mean;
        float rstd = rsqrtf(var + EPSV);
        float nrm = (f - mean) * rstd * flnw[t] + flnb[t];
        gl_s[t] = geluf(nrm);
    }
    __syncthreads();
    float o = f2b[t];
    {
        const float4* wr = reinterpret_cast<const float4*>(f2w + (size_t)t * 128);
        const float4* gr = reinterpret_cast<const float4*>(gl_s);
        #pragma unroll 8
        for (int kq = 0; kq < 32; ++kq) {
            float4 w = wr[kq], gg = gr[kq];
            o += w.x * gg.x + w.y * gg.y + w.z * gg.z + w.w * gg.w;
        }
    }
    out[((size_t)b * 128 + t) * NN + i] = tok[row + t] + o;
}

extern "C" void kernel_launch(void* const* d_in, const int* in_sizes, int n_in,
                              void* d_out, int out_size, void* d_ws, size_t ws_size,
                              hipStream_t stream) {
    const float* x         = (const float*)d_in[0];
    const float* mha_in_w  = (const float*)d_in[1];
    const float* mha_in_b  = (const float*)d_in[2];
    const float* mha_out_w = (const float*)d_in[3];
    const float* mha_out_b = (const float*)d_in[4];
    const float* gv_w[2]  = {(const float*)d_in[5],  (const float*)d_in[17]};
    const float* gv_b[2]  = {(const float*)d_in[6],  (const float*)d_in[18]};
    const float* ge1_w[2] = {(const float*)d_in[7],  (const float*)d_in[19]};
    const float* ge1_b[2] = {(const float*)d_in[8],  (const float*)d_in[20]};
    const float* geln_w[2]= {(const float*)d_in[9],  (const float*)d_in[21]};
    const float* geln_b[2]= {(const float*)d_in[10], (const float*)d_in[22]};
    const float* ge2_w[2] = {(const float*)d_in[11], (const float*)d_in[23]};
    const float* ge2_b[2] = {(const float*)d_in[12], (const float*)d_in[24]};
    const float* go_w[2]  = {(const float*)d_in[13], (const float*)d_in[25]};
    const float* go_b[2]  = {(const float*)d_in[14], (const float*)d_in[26]};
    const float* gn_w[2]  = {(const float*)d_in[15], (const float*)d_in[27]};
    const float* gn_b[2]  = {(const float*)d_in[16], (const float*)d_in[28]};
    const float* n1w = (const float*)d_in[29];
    const float* n1b = (const float*)d_in[30];
    const float* n2w = (const float*)d_in[31];
    const float* n2b = (const float*)d_in[32];
    const float* f1w = (const float*)d_in[33];
    const float* f1b = (const float*)d_in[34];
    const float* flnw = (const float*)d_in[35];
    const float* flnb = (const float*)d_in[36];
    const float* f2w = (const float*)d_in[37];
    const float* f2b = (const float*)d_in[38];

    float* ws     = (float*)d_ws;
    float* tokens = ws;                       // 147456
    float* attn   = tokens + 147456;          // 147456
    float* g      = attn + 147456;            // 147456
    float* qkv    = g + 147456;               // 442368 (qkv / ua|wb|v interleaved)
    float* kT     = qkv + 442368;             // 147456
    float* wTq    = kT + 147456;              // 49152
    float* wT0    = wTq + 49152;              // 49152
    float* wT1    = wT0 + 49152;              // 49152
    __half* ewh   = (__half*)(wT1 + 49152);   // 2654208 halfs = 5.3 MB

    k_tok<<<dim3(288, 2), 256, 0, stream>>>(x, tokens);
    k_wtrq<<<192, 256, 0, stream>>>(mha_in_w, wTq);
    k_wtr<<<192, 256, 0, stream>>>(ge1_w[0], gv_w[0], wT0);
    k_wtr<<<192, 256, 0, stream>>>(ge1_w[1], gv_w[1], wT1);

    k_gemmT<<<288, 384, 0, stream>>>(tokens, wTq, mha_in_b, mha_in_b + 128, mha_in_b + 256, qkv);
    k_ktr<<<576, 256, 0, stream>>>(qkv, kT);
    k_mha2<<<1152, 256, 0, stream>>>(tokens, qkv, kT, mha_out_w, mha_out_b, n1w, n1b, attn);

    for (int l = 0; l < 2; ++l) {
        const float* xin = (l == 0) ? attn : g;
        const float* wTl = (l == 0) ? wT0 : wT1;
        k_gemmT<<<288, 384, 0, stream>>>(xin, wTl, nullptr, nullptr, gv_b[l], qkv);
        k_center<<<288, 256, 0, stream>>>(qkv, 0, nullptr);
        k_center<<<288, 256, 0, stream>>>(qkv, 128, ge1_b[l]);
        k_edge<<<dim3(36, 36, 2), 256, 0, stream>>>(qkv, geln_w[l], geln_b[l],
                                                    ge2_w[l], ge2_b[l], ewh);
        k_gcn_agg<<<1152, 256, 0, stream>>>(xin, qkv, ewh, go_w[l], go_b[l],
                                            gn_w[l], gn_b[l], g);
    }
    k_final<<<1152, 128, 0, stream>>>(tokens, attn, g, n2w, n2b,
        f1w, f1b, flnw, flnb, f2w, f2b, (float*)d_out);
}

// Round 3
// 478.699 us; speedup vs baseline: 2.7151x; 1.2712x over previous
//
#include <hip/hip_runtime.h>
#include <hip/hip_fp16.h>
#include <math.h>

#define NN 576
#define EPSV 1e-5f

// exact gelu (erf) — used only where cheap (k_final)
__device__ __forceinline__ float gelu_exact(float x) {
    return 0.5f * x * (1.0f + erff(x * 0.70710678118654752f));
}
// fast tanh-approx gelu via hardware exp — used in the 85M-gelu edge kernel
__device__ __forceinline__ float gelu_fast(float x) {
    float u = x * (0.7978845608028654f + 0.0356774081f * x * x);
    float e = __expf(2.0f * u);
    float th = 1.0f - 2.0f / (e + 1.0f);
    return 0.5f * x * (1.0f + th);
}

// x (B,C,HW) -> tokens (B,HW,C)
__global__ void k_tok(const float* __restrict__ x, float* __restrict__ tok) {
    int b = blockIdx.y;
    int idx = blockIdx.x * 256 + threadIdx.x;
    if (idx < NN * 128) {
        int n = idx >> 7, c = idx & 127;
        tok[(size_t)b * NN * 128 + idx] = x[((size_t)b * 128 + c) * NN + n];
    }
}

// wT[k*384+o] = mha_in_w[o*128+k]
__global__ void k_wtrq(const float* __restrict__ w, float* __restrict__ dst) {
    int idx = blockIdx.x * 256 + threadIdx.x;
    int k = idx / 384, o = idx - k * 384;
    dst[idx] = w[o * 128 + k];
}

// combined layer weight: cols 0..127 = w1a, 128..255 = w1b, 256..383 = v_w
__global__ void k_wtr(const float* __restrict__ e1w, const float* __restrict__ vw,
                      float* __restrict__ dst) {
    int idx = blockIdx.x * 256 + threadIdx.x;
    int k = idx / 384, o = idx - k * 384;
    float v;
    if (o < 128)      v = e1w[o * 256 + k];
    else if (o < 256) v = e1w[(o - 128) * 256 + 128 + k];
    else              v = vw[(o - 256) * 128 + k];
    dst[idx] = v;
}

// out[r, o] = sum_k A[r,k]*wT[k*384+o] (+bias chunk), 4 rows/block, 384 threads
__global__ __launch_bounds__(384) void k_gemmT(
    const float* __restrict__ A, const float* __restrict__ wT,
    const float* __restrict__ b0, const float* __restrict__ b1, const float* __restrict__ b2,
    float* __restrict__ out)
{
    const int t = threadIdx.x;
    const int r0 = blockIdx.x * 4;
    __shared__ float a_s[4][132];
    if (t < 128) {
        float4 v = *(const float4*)(A + (size_t)(r0 + (t >> 5)) * 128 + (t & 31) * 4);
        *(float4*)&a_s[t >> 5][(t & 31) * 4] = v;
    }
    __syncthreads();
    float acc0 = 0.f, acc1 = 0.f, acc2 = 0.f, acc3 = 0.f;
    #pragma unroll 8
    for (int k = 0; k < 128; ++k) {
        float w = wT[(size_t)k * 384 + t];
        acc0 += a_s[0][k] * w;
        acc1 += a_s[1][k] * w;
        acc2 += a_s[2][k] * w;
        acc3 += a_s[3][k] * w;
    }
    const float* bp = (t < 128) ? b0 : ((t < 256) ? b1 : b2);
    float bv = bp ? bp[t & 127] : 0.f;
    out[(size_t)(r0 + 0) * 384 + t] = acc0 + bv;
    out[(size_t)(r0 + 1) * 384 + t] = acc1 + bv;
    out[(size_t)(r0 + 2) * 384 + t] = acc2 + bv;
    out[(size_t)(r0 + 3) * 384 + t] = acc3 + bv;
}

// in-place row centering: row -= mean(row (+bias))
__global__ __launch_bounds__(256) void k_center(float* __restrict__ buf, int off,
                                                const float* __restrict__ bias) {
    int row = blockIdx.x * 4 + (threadIdx.x >> 6);
    int lane = threadIdx.x & 63;
    float* p = buf + (size_t)row * 384 + off + lane * 2;
    float2 v = *(float2*)p;
    if (bias) { v.x += bias[lane * 2]; v.y += bias[lane * 2 + 1]; }
    float s = v.x + v.y;
    #pragma unroll
    for (int o = 32; o > 0; o >>= 1) s += __shfl_xor(s, o);
    float m = s * (1.0f / 128.0f);
    float2 r; r.x = v.x - m; r.y = v.y - m;
    *(float2*)p = r;
}

// MHA scores, pair-tile: one thread per (i,j), all 8 heads. sc fp16 [b][i][j][8]
__global__ __launch_bounds__(256) void k_score(
    const float* __restrict__ qkv, __half* __restrict__ sc)
{
    const int jt = blockIdx.x, it = blockIdx.y, b = blockIdx.z;
    const int i0 = it * 16, j0 = jt * 16;
    const int t = threadIdx.x;
    __shared__ float q_s[16][132], k_s[16][132];
    for (int idx = t; idx < 512; idx += 256) {
        int r = idx >> 5, cq = idx & 31;
        float4 qv = *(const float4*)(qkv + (size_t)(b * NN + i0 + r) * 384 + cq * 4);
        qv.x *= 0.25f; qv.y *= 0.25f; qv.z *= 0.25f; qv.w *= 0.25f;
        *(float4*)&q_s[r][cq * 4] = qv;
        *(float4*)&k_s[r][cq * 4] = *(const float4*)(qkv + (size_t)(b * NN + j0 + r) * 384 + 128 + cq * 4);
    }
    __syncthreads();
    const int ti = t >> 4, tj = t & 15;
    const float4* qr = (const float4*)q_s[ti];
    const float4* kr = (const float4*)k_s[tj];
    float acc[8] = {0.f,0.f,0.f,0.f,0.f,0.f,0.f,0.f};
    #pragma unroll
    for (int cq = 0; cq < 32; ++cq) {
        float4 q = qr[cq], k = kr[cq];
        acc[cq >> 2] += q.x * k.x + q.y * k.y + q.z * k.z + q.w * k.w;
    }
    __half2 h[4];
    #pragma unroll
    for (int p = 0; p < 4; ++p) h[p] = __floats2half2_rn(acc[2 * p], acc[2 * p + 1]);
    *(uint4*)(sc + ((size_t)(b * NN + i0 + ti) * NN + j0 + tj) * 8) = *(uint4*)h;
}

// MHA per (b,i): softmax (8 heads) + AV + o-proj + residual + LN
__global__ __launch_bounds__(256) void k_mha_agg(
    const float* __restrict__ tok, const float* __restrict__ qkv,
    const __half* __restrict__ sc,
    const float* __restrict__ ow, const float* __restrict__ ob,
    const float* __restrict__ nw, const float* __restrict__ nb,
    float* __restrict__ attn)
{
    const int bi = blockIdx.x;
    const int b = bi / NN, i = bi - b * NN;
    const int t = threadIdx.x;
    const int jl = t & 63, q = t >> 6;

    __shared__ float s_s[576][9];
    __shared__ float inv_s[8];
    __shared__ float aggp[2][128];
    __shared__ float agg_s[128];
    __shared__ float red1[4], red2[4];

    const __half* srow = sc + (size_t)(b * NN + i) * NN * 8;
    for (int j = t; j < NN; j += 256) {
        uint4 raw = *(const uint4*)(srow + j * 8);
        const __half2* hp = (const __half2*)&raw;
        #pragma unroll
        for (int p = 0; p < 4; ++p) {
            s_s[j][2 * p]     = __low2float(hp[p]);
            s_s[j][2 * p + 1] = __high2float(hp[p]);
        }
    }
    __syncthreads();
    #pragma unroll
    for (int hh = 0; hh < 2; ++hh) {
        int h = q * 2 + hh;
        float mx = -1e30f;
        for (int j = jl; j < NN; j += 64) mx = fmaxf(mx, s_s[j][h]);
        #pragma unroll
        for (int off = 32; off > 0; off >>= 1) mx = fmaxf(mx, __shfl_xor(mx, off));
        float sm = 0.f;
        for (int j = jl; j < NN; j += 64) {
            float e = __expf(s_s[j][h] - mx);
            s_s[j][h] = e;
            sm += e;
        }
        #pragma unroll
        for (int off = 32; off > 0; off >>= 1) sm += __shfl_xor(sm, off);
        if (jl == 0) inv_s[h] = 1.0f / sm;
    }
    __syncthreads();
    {
        const int c = t & 127, half = t >> 7;
        const int h = c >> 4;
        float acc = 0.f;
        for (int j = half; j < NN; j += 2)
            acc += s_s[j][h] * qkv[(size_t)(b * NN + j) * 384 + 256 + c];
        aggp[half][c] = acc;
    }
    __syncthreads();
    if (t < 128) agg_s[t] = (aggp[0][t] + aggp[1][t]) * inv_s[t >> 4];
    __syncthreads();
    float val = 0.f;
    if (t < 128) {
        float o = ob[t];
        const float4* wrow = reinterpret_cast<const float4*>(ow + (size_t)t * 128);
        const float4* ar = reinterpret_cast<const float4*>(agg_s);
        #pragma unroll 8
        for (int kq = 0; kq < 32; ++kq) {
            float4 w = wrow[kq], a = ar[kq];
            o += w.x * a.x + w.y * a.y + w.z * a.z + w.w * a.w;
        }
        val = o + tok[(size_t)(b * NN + i) * 128 + t];
    }
    float s1 = val, s2 = val * val;
    #pragma unroll
    for (int off = 32; off > 0; off >>= 1) {
        s1 += __shfl_xor(s1, off);
        s2 += __shfl_xor(s2, off);
    }
    if (jl == 0) { red1[q] = s1; red2[q] = s2; }
    __syncthreads();
    float tot1 = red1[0] + red1[1] + red1[2] + red1[3];
    float tot2 = red2[0] + red2[1] + red2[2] + red2[3];
    float mean = tot1 * (1.0f / 128.0f);
    float var = tot2 * (1.0f / 128.0f) - mean * mean;
    float rstd = rsqrtf(var + EPSV);
    if (t < 128) {
        attn[(size_t)(b * NN + i) * 128 + t] = (val - mean) * rstd * nw[t] + nb[t];
    }
}

// Edge MLP: one thread per (i,j) pair, 16x16 tile per block. No reductions.
__global__ __launch_bounds__(256) void k_edge(
    const float* __restrict__ abv,
    const float* __restrict__ elnw, const float* __restrict__ elnb,
    const float* __restrict__ e2w, const float* __restrict__ e2b,
    __half* __restrict__ ew)
{
    const int jt = blockIdx.x, it = blockIdx.y, b = blockIdx.z;
    const int i0 = it * 16, j0 = jt * 16;
    const int t = threadIdx.x;
    __shared__ float ua_s[16][132], wb_s[16][132];

    for (int idx = t; idx < 512; idx += 256) {
        int r = idx >> 5, cq = idx & 31;
        *(float4*)&ua_s[r][cq * 4] = *(const float4*)(abv + (size_t)(b * NN + i0 + r) * 384 + cq * 4);
        *(float4*)&wb_s[r][cq * 4] = *(const float4*)(abv + (size_t)(b * NN + j0 + r) * 384 + 128 + cq * 4);
    }
    __syncthreads();

    const int ti = t >> 4, tj = t & 15;
    const float4* uar = (const float4*)ua_s[ti];
    const float4* wbr = (const float4*)wb_s[tj];

    float s2 = 0.f;
    #pragma unroll
    for (int cq = 0; cq < 32; ++cq) {
        float4 u = uar[cq], w = wbr[cq];
        float e0 = u.x + w.x, e1 = u.y + w.y, e2v = u.z + w.z, e3 = u.w + w.w;
        s2 += e0 * e0 + e1 * e1 + e2v * e2v + e3 * e3;
    }
    float rstd = rsqrtf(s2 * (1.0f / 128.0f) + EPSV);

    float p0 = 0.f, p1 = 0.f, p2 = 0.f, p3 = 0.f;
    #pragma unroll 4
    for (int cq = 0; cq < 32; ++cq) {
        float4 u = uar[cq], w = wbr[cq];
        float4 lw = ((const float4*)elnw)[cq];
        float4 lb = ((const float4*)elnb)[cq];
        float4 q0 = ((const float4*)(e2w))[cq];
        float4 q1 = ((const float4*)(e2w + 128))[cq];
        float4 q2 = ((const float4*)(e2w + 256))[cq];
        float4 q3 = ((const float4*)(e2w + 384))[cq];
        float g;
        g = gelu_fast((u.x + w.x) * rstd * lw.x + lb.x); p0 += g * q0.x; p1 += g * q1.x; p2 += g * q2.x; p3 += g * q3.x;
        g = gelu_fast((u.y + w.y) * rstd * lw.y + lb.y); p0 += g * q0.y; p1 += g * q1.y; p2 += g * q2.y; p3 += g * q3.y;
        g = gelu_fast((u.z + w.z) * rstd * lw.z + lb.z); p0 += g * q0.z; p1 += g * q1.z; p2 += g * q2.z; p3 += g * q3.z;
        g = gelu_fast((u.w + w.w) * rstd * lw.w + lb.w); p0 += g * q0.w; p1 += g * q1.w; p2 += g * q2.w; p3 += g * q3.w;
    }
    __half2 h01 = __floats2half2_rn(p0 + e2b[0], p1 + e2b[1]);
    __half2 h23 = __floats2half2_rn(p2 + e2b[2], p3 + e2b[3]);
    __half* dst = ew + ((size_t)(b * NN + i0 + ti) * NN + j0 + tj) * 4;
    *(__half2*)dst = h01;
    *(__half2*)(dst + 2) = h23;
}

// per (b,i): softmax over j per head + AV + o-proj + residual + LN
__global__ __launch_bounds__(256) void k_gcn_agg(
    const float* __restrict__ xin, const float* __restrict__ abv,
    const __half* __restrict__ ew,
    const float* __restrict__ ow, const float* __restrict__ ob,
    const float* __restrict__ nw, const float* __restrict__ nb,
    float* __restrict__ gout)
{
    const int bi = blockIdx.x;
    const int b = bi / NN, i = bi - b * NN;
    const int t = threadIdx.x;
    const int jl = t & 63, q = t >> 6;

    __shared__ float ew_s[576][5];
    __shared__ float inv_s[4];
    __shared__ float aggp[2][128];
    __shared__ float agg_s[128];
    __shared__ float red1[4], red2[4];

    const __half* ewb = ew + (size_t)(b * NN + i) * NN * 4;
    for (int j = t; j < NN; j += 256) {
        uint2 raw = *(const uint2*)(ewb + j * 4);
        __half2 h01 = *(__half2*)&raw.x;
        __half2 h23 = *(__half2*)&raw.y;
        ew_s[j][0] = __low2float(h01);
        ew_s[j][1] = __high2float(h01);
        ew_s[j][2] = __low2float(h23);
        ew_s[j][3] = __high2float(h23);
    }
    __syncthreads();
    {
        float mx = -1e30f;
        for (int j = jl; j < NN; j += 64) mx = fmaxf(mx, ew_s[j][q]);
        #pragma unroll
        for (int off = 32; off > 0; off >>= 1) mx = fmaxf(mx, __shfl_xor(mx, off));
        float sm = 0.f;
        for (int j = jl; j < NN; j += 64) {
            float e = __expf(ew_s[j][q] - mx);
            ew_s[j][q] = e;
            sm += e;
        }
        #pragma unroll
        for (int off = 32; off > 0; off >>= 1) sm += __shfl_xor(sm, off);
        if (jl == 0) inv_s[q] = 1.0f / sm;
    }
    __syncthreads();
    {
        const int c = t & 127, half = t >> 7;
        const int h = c >> 5;
        float acc = 0.f;
        for (int j = half; j < NN; j += 2)
            acc += ew_s[j][h] * abv[(size_t)(b * NN + j) * 384 + 256 + c];
        aggp[half][c] = acc;
    }
    __syncthreads();
    if (t < 128) agg_s[t] = (aggp[0][t] + aggp[1][t]) * inv_s[t >> 5];
    __syncthreads();
    float val = 0.f;
    if (t < 128) {
        float o = ob[t];
        const float4* wrow = reinterpret_cast<const float4*>(ow + (size_t)t * 128);
        const float4* ar = reinterpret_cast<const float4*>(agg_s);
        #pragma unroll 8
        for (int kq = 0; kq < 32; ++kq) {
            float4 w = wrow[kq], a = ar[kq];
            o += w.x * a.x + w.y * a.y + w.z * a.z + w.w * a.w;
        }
        val = o + xin[(size_t)(b * NN + i) * 128 + t];
    }
    float s1 = val, s2 = val * val;
    #pragma unroll
    for (int off = 32; off > 0; off >>= 1) {
        s1 += __shfl_xor(s1, off);
        s2 += __shfl_xor(s2, off);
    }
    if (jl == 0) { red1[q] = s1; red2[q] = s2; }
    __syncthreads();
    float tot1 = red1[0] + red1[1] + red1[2] + red1[3];
    float tot2 = red2[0] + red2[1] + red2[2] + red2[3];
    float mean = tot1 * (1.0f / 128.0f);
    float var = tot2 * (1.0f / 128.0f) - mean * mean;
    float rstd = rsqrtf(var + EPSV);
    if (t < 128) {
        gout[(size_t)(b * NN + i) * 128 + t] = (val - mean) * rstd * nw[t] + nb[t];
    }
}

// Final: LN(n2) on g, concat, f1 + LN + gelu + f2, + tokens, write (B,C,H,W)
__global__ __launch_bounds__(128) void k_final(
    const float* __restrict__ tok, const float* __restrict__ attn, const float* __restrict__ g,
    const float* __restrict__ n2w, const float* __restrict__ n2b,
    const float* __restrict__ f1w, const float* __restrict__ f1b,
    const float* __restrict__ flnw, const float* __restrict__ flnb,
    const float* __restrict__ f2w, const float* __restrict__ f2b,
    float* __restrict__ out)
{
    const int bi = blockIdx.x;
    const int b = bi / NN, i = bi - b * NN;
    const int t = threadIdx.x;
    __shared__ float cat_s[256];
    __shared__ float gl_s[128];
    __shared__ float red1[2], red2[2];

    const size_t row = (size_t)(b * NN + i) * 128;
    cat_s[t] = attn[row + t];
    float gv = g[row + t];
    {
        float s1 = gv, s2 = gv * gv;
        #pragma unroll
        for (int off = 32; off > 0; off >>= 1) { s1 += __shfl_xor(s1, off); s2 += __shfl_xor(s2, off); }
        if ((t & 63) == 0) { red1[t >> 6] = s1; red2[t >> 6] = s2; }
        __syncthreads();
        float mean = (red1[0] + red1[1]) * (1.0f / 128.0f);
        float var = (red2[0] + red2[1]) * (1.0f / 128.0f) - mean * mean;
        float rstd = rsqrtf(var + EPSV);
        cat_s[128 + t] = (gv - mean) * rstd * n2w[t] + n2b[t];
    }
    __syncthreads();
    float f = f1b[t];
    {
        const float4* wr = reinterpret_cast<const float4*>(f1w + (size_t)t * 256);
        const float4* cr = reinterpret_cast<const float4*>(cat_s);
        #pragma unroll 8
        for (int kq = 0; kq < 64; ++kq) {
            float4 w = wr[kq], c = cr[kq];
            f += w.x * c.x + w.y * c.y + w.z * c.z + w.w * c.w;
        }
    }
    {
        float s1 = f, s2 = f * f;
        #pragma unroll
        for (int off = 32; off > 0; off >>= 1) { s1 += __shfl_xor(s1, off); s2 += __shfl_xor(s2, off); }
        __syncthreads();
        if ((t & 63) == 0) { red1[t >> 6] = s1; red2[t >> 6] = s2; }
        __syncthreads();
        float mean = (red1[0] + red1[1]) * (1.0f / 128.0f);
        float var = (red2[0] + red2[1]) * (1.0f / 128.0f) - mean * mean;
        float rstd = rsqrtf(var + EPSV);
        float nrm = (f - mean) * rstd * flnw[t] + flnb[t];
        gl_s[t] = gelu_exact(nrm);
    }
    __syncthreads();
    float o = f2b[t];
    {
        const float4* wr = reinterpret_cast<const float4*>(f2w + (size_t)t * 128);
        const float4* gr = reinterpret_cast<const float4*>(gl_s);
        #pragma unroll 8
        for (int kq = 0; kq < 32; ++kq) {
            float4 w = wr[kq], gg = gr[kq];
            o += w.x * gg.x + w.y * gg.y + w.z * gg.z + w.w * gg.w;
        }
    }
    out[((size_t)b * 128 + t) * NN + i] = tok[row + t] + o;
}

extern "C" void kernel_launch(void* const* d_in, const int* in_sizes, int n_in,
                              void* d_out, int out_size, void* d_ws, size_t ws_size,
                              hipStream_t stream) {
    const float* x         = (const float*)d_in[0];
    const float* mha_in_b  = (const float*)d_in[2];
    const float* mha_out_w = (const float*)d_in[3];
    const float* mha_out_b = (const float*)d_in[4];
    const float* gv_w[2]  = {(const float*)d_in[5],  (const float*)d_in[17]};
    const float* gv_b[2]  = {(const float*)d_in[6],  (const float*)d_in[18]};
    const float* ge1_w[2] = {(const float*)d_in[7],  (const float*)d_in[19]};
    const float* ge1_b[2] = {(const float*)d_in[8],  (const float*)d_in[20]};
    const float* geln_w[2]= {(const float*)d_in[9],  (const float*)d_in[21]};
    const float* geln_b[2]= {(const float*)d_in[10], (const float*)d_in[22]};
    const float* ge2_w[2] = {(const float*)d_in[11], (const float*)d_in[23]};
    const float* ge2_b[2] = {(const float*)d_in[12], (const float*)d_in[24]};
    const float* go_w[2]  = {(const float*)d_in[13], (const float*)d_in[25]};
    const float* go_b[2]  = {(const float*)d_in[14], (const float*)d_in[26]};
    const float* gn_w[2]  = {(const float*)d_in[15], (const float*)d_in[27]};
    const float* gn_b[2]  = {(const float*)d_in[16], (const float*)d_in[28]};
    const float* n1w = (const float*)d_in[29];
    const float* n1b = (const float*)d_in[30];
    const float* n2w = (const float*)d_in[31];
    const float* n2b = (const float*)d_in[32];
    const float* f1w = (const float*)d_in[33];
    const float* f1b = (const float*)d_in[34];
    const float* flnw = (const float*)d_in[35];
    const float* flnb = (const float*)d_in[36];
    const float* f2w = (const float*)d_in[37];
    const float* f2b = (const float*)d_in[38];

    float* ws     = (float*)d_ws;
    float* tokens = ws;                       // 147456
    float* attn   = tokens + 147456;          // 147456
    float* g      = attn + 147456;            // 147456
    float* qkv    = g + 147456;               // 442368
    float* wTq    = qkv + 442368;             // 49152
    float* wT0    = wTq + 49152;              // 49152
    float* wT1    = wT0 + 49152;              // 49152
    // fp16 region: sc [2*576*576*8] (MHA scores) aliases ewh [2*576*576*4]
    // (GCN edge logits) — sc is fully consumed before the first k_edge write.
    __half* sc    = (__half*)(wT1 + 49152);   // 5308416 halfs = 10.6 MB
    __half* ewh   = sc;

    k_tok<<<dim3(288, 2), 256, 0, stream>>>(x, tokens);
    k_wtrq<<<192, 256, 0, stream>>>((const float*)d_in[1], wTq);
    k_wtr<<<192, 256, 0, stream>>>(ge1_w[0], gv_w[0], wT0);
    k_wtr<<<192, 256, 0, stream>>>(ge1_w[1], gv_w[1], wT1);

    k_gemmT<<<288, 384, 0, stream>>>(tokens, wTq, mha_in_b, mha_in_b + 128, mha_in_b + 256, qkv);
    k_score<<<dim3(36, 36, 2), 256, 0, stream>>>(qkv, sc);
    k_mha_agg<<<1152, 256, 0, stream>>>(tokens, qkv, sc, mha_out_w, mha_out_b, n1w, n1b, attn);

    for (int l = 0; l < 2; ++l) {
        const float* xin = (l == 0) ? attn : g;
        const float* wTl = (l == 0) ? wT0 : wT1;
        k_gemmT<<<288, 384, 0, stream>>>(xin, wTl, nullptr, nullptr, gv_b[l], qkv);
        k_center<<<288, 256, 0, stream>>>(qkv, 0, nullptr);
        k_center<<<288, 256, 0, stream>>>(qkv, 128, ge1_b[l]);
        k_edge<<<dim3(36, 36, 2), 256, 0, stream>>>(qkv, geln_w[l], geln_b[l],
                                                    ge2_w[l], ge2_b[l], ewh);
        k_gcn_agg<<<1152, 256, 0, stream>>>(xin, qkv, ewh, go_w[l], go_b[l],
                                            gn_w[l], gn_b[l], g);
    }
    k_final<<<1152, 128, 0, stream>>>(tokens, attn, g, n2w, n2b,
        f1w, f1b, flnw, flnb, f2w, f2b, (float*)d_out);
}

// Round 4
// 306.659 us; speedup vs baseline: 4.2383x; 1.5610x over previous
//
#include <hip/hip_runtime.h>
#include <hip/hip_fp16.h>
#include <math.h>

#define NN 576
#define EPSV 1e-5f

__device__ __forceinline__ float gelu_exact(float x) {
    return 0.5f * x * (1.0f + erff(x * 0.70710678118654752f));
}
__device__ __forceinline__ float gelu_fast(float x) {
    float u = x * (0.7978845608028654f + 0.0356774081f * x * x);
    float e = __expf(2.0f * u);
    float th = 1.0f - 2.0f / (e + 1.0f);
    return 0.5f * x * (1.0f + th);
}

// x (B,C,HW) -> tokens (B,HW,C)
__global__ void k_tok(const float* __restrict__ x, float* __restrict__ tok) {
    int b = blockIdx.y;
    int idx = blockIdx.x * 256 + threadIdx.x;
    if (idx < NN * 128) {
        int n = idx >> 7, c = idx & 127;
        tok[(size_t)b * NN * 128 + idx] = x[((size_t)b * 128 + c) * NN + n];
    }
}

// merged weight transposes: y=0 -> wTq (mha_in_w), y=1 -> wT0, y=2 -> wT1
__global__ void k_prep(const float* __restrict__ mha_in_w,
                       const float* __restrict__ e1w0, const float* __restrict__ vw0,
                       const float* __restrict__ e1w1, const float* __restrict__ vw1,
                       float* __restrict__ wTq, float* __restrict__ wT0, float* __restrict__ wT1) {
    int which = blockIdx.y;
    int idx = blockIdx.x * 256 + threadIdx.x;   // 49152
    int k = idx / 384, o = idx - k * 384;
    if (which == 0) {
        wTq[idx] = mha_in_w[o * 128 + k];
    } else {
        const float* e1w = (which == 1) ? e1w0 : e1w1;
        const float* vw  = (which == 1) ? vw0  : vw1;
        float v;
        if (o < 128)      v = e1w[o * 256 + k];
        else if (o < 256) v = e1w[(o - 128) * 256 + 128 + k];
        else              v = vw[(o - 256) * 128 + k];
        ((which == 1) ? wT0 : wT1)[idx] = v;
    }
}

// out[r, o] = sum_k A[r,k]*wT[k*384+o] + bias chunk; optional per-row centering
// of chunks 0 and 1 (mean over 128 channels, bias included). 4 rows, 384 thr.
template<bool CENTER>
__global__ __launch_bounds__(384) void k_gemmT(
    const float* __restrict__ A, const float* __restrict__ wT,
    const float* __restrict__ b0, const float* __restrict__ b1, const float* __restrict__ b2,
    float* __restrict__ out)
{
    const int t = threadIdx.x;
    const int r0 = blockIdx.x * 4;
    __shared__ float a_s[4][132];
    if (t < 128) {
        float4 v = *(const float4*)(A + (size_t)(r0 + (t >> 5)) * 128 + (t & 31) * 4);
        *(float4*)&a_s[t >> 5][(t & 31) * 4] = v;
    }
    __syncthreads();
    float acc[4] = {0.f, 0.f, 0.f, 0.f};
    #pragma unroll 8
    for (int k = 0; k < 128; ++k) {
        float w = wT[(size_t)k * 384 + t];
        acc[0] += a_s[0][k] * w;
        acc[1] += a_s[1][k] * w;
        acc[2] += a_s[2][k] * w;
        acc[3] += a_s[3][k] * w;
    }
    const float* bp = (t < 128) ? b0 : ((t < 256) ? b1 : b2);
    float bv = bp ? bp[t & 127] : 0.f;
    #pragma unroll
    for (int r = 0; r < 4; ++r) acc[r] += bv;

    if (CENTER) {
        // wave w covers: 0,1 -> chunk0; 2,3 -> chunk1; 4,5 -> chunk2 (no center)
        __shared__ float redc[6][4];
        const int wv = t >> 6, ln = t & 63;
        #pragma unroll
        for (int r = 0; r < 4; ++r) {
            float xr = acc[r];
            #pragma unroll
            for (int off = 32; off > 0; off >>= 1) xr += __shfl_xor(xr, off);
            if (ln == 0) redc[wv][r] = xr;
        }
        __syncthreads();
        if (t < 256) {
            const int ch = t >> 7;   // 0 or 1
            #pragma unroll
            for (int r = 0; r < 4; ++r) {
                float mean = (redc[2 * ch][r] + redc[2 * ch + 1][r]) * (1.0f / 128.0f);
                acc[r] -= mean;
            }
        }
    }
    #pragma unroll
    for (int r = 0; r < 4; ++r)
        out[(size_t)(r0 + r) * 384 + t] = acc[r];
}

// MHA scores, pair-tile: one thread per (i,j), all 8 heads. sc fp16 [b][i][j][8]
__global__ __launch_bounds__(256) void k_score(
    const float* __restrict__ qkv, __half* __restrict__ sc)
{
    const int jt = blockIdx.x, it = blockIdx.y, b = blockIdx.z;
    const int i0 = it * 16, j0 = jt * 16;
    const int t = threadIdx.x;
    __shared__ float q_s[16][132], k_s[16][132];
    for (int idx = t; idx < 512; idx += 256) {
        int r = idx >> 5, cq = idx & 31;
        float4 qv = *(const float4*)(qkv + (size_t)(b * NN + i0 + r) * 384 + cq * 4);
        qv.x *= 0.25f; qv.y *= 0.25f; qv.z *= 0.25f; qv.w *= 0.25f;
        *(float4*)&q_s[r][cq * 4] = qv;
        *(float4*)&k_s[r][cq * 4] = *(const float4*)(qkv + (size_t)(b * NN + j0 + r) * 384 + 128 + cq * 4);
    }
    __syncthreads();
    const int ti = t >> 4, tj = t & 15;
    const float4* qr = (const float4*)q_s[ti];
    const float4* kr = (const float4*)k_s[tj];
    float acc[8] = {0.f,0.f,0.f,0.f,0.f,0.f,0.f,0.f};
    #pragma unroll
    for (int cq = 0; cq < 32; ++cq) {
        float4 q = qr[cq], k = kr[cq];
        acc[cq >> 2] += q.x * k.x + q.y * k.y + q.z * k.z + q.w * k.w;
    }
    __half2 h[4];
    #pragma unroll
    for (int p = 0; p < 4; ++p) h[p] = __floats2half2_rn(acc[2 * p], acc[2 * p + 1]);
    *(uint4*)(sc + ((size_t)(b * NN + i0 + ti) * NN + j0 + tj) * 8) = *(uint4*)h;
}

// Edge MLP: one thread per (i,j) pair, 16x16 tile per block. No reductions.
__global__ __launch_bounds__(256) void k_edge(
    const float* __restrict__ abv,
    const float* __restrict__ elnw, const float* __restrict__ elnb,
    const float* __restrict__ e2w, const float* __restrict__ e2b,
    __half* __restrict__ ew)
{
    const int jt = blockIdx.x, it = blockIdx.y, b = blockIdx.z;
    const int i0 = it * 16, j0 = jt * 16;
    const int t = threadIdx.x;
    __shared__ float ua_s[16][132], wb_s[16][132];

    for (int idx = t; idx < 512; idx += 256) {
        int r = idx >> 5, cq = idx & 31;
        *(float4*)&ua_s[r][cq * 4] = *(const float4*)(abv + (size_t)(b * NN + i0 + r) * 384 + cq * 4);
        *(float4*)&wb_s[r][cq * 4] = *(const float4*)(abv + (size_t)(b * NN + j0 + r) * 384 + 128 + cq * 4);
    }
    __syncthreads();

    const int ti = t >> 4, tj = t & 15;
    const float4* uar = (const float4*)ua_s[ti];
    const float4* wbr = (const float4*)wb_s[tj];

    float s2 = 0.f;
    #pragma unroll
    for (int cq = 0; cq < 32; ++cq) {
        float4 u = uar[cq], w = wbr[cq];
        float e0 = u.x + w.x, e1 = u.y + w.y, e2v = u.z + w.z, e3 = u.w + w.w;
        s2 += e0 * e0 + e1 * e1 + e2v * e2v + e3 * e3;
    }
    float rstd = rsqrtf(s2 * (1.0f / 128.0f) + EPSV);

    float p0 = 0.f, p1 = 0.f, p2 = 0.f, p3 = 0.f;
    #pragma unroll 4
    for (int cq = 0; cq < 32; ++cq) {
        float4 u = uar[cq], w = wbr[cq];
        float4 lw = ((const float4*)elnw)[cq];
        float4 lb = ((const float4*)elnb)[cq];
        float4 q0 = ((const float4*)(e2w))[cq];
        float4 q1 = ((const float4*)(e2w + 128))[cq];
        float4 q2 = ((const float4*)(e2w + 256))[cq];
        float4 q3 = ((const float4*)(e2w + 384))[cq];
        float g;
        g = gelu_fast((u.x + w.x) * rstd * lw.x + lb.x); p0 += g * q0.x; p1 += g * q1.x; p2 += g * q2.x; p3 += g * q3.x;
        g = gelu_fast((u.y + w.y) * rstd * lw.y + lb.y); p0 += g * q0.y; p1 += g * q1.y; p2 += g * q2.y; p3 += g * q3.y;
        g = gelu_fast((u.z + w.z) * rstd * lw.z + lb.z); p0 += g * q0.z; p1 += g * q1.z; p2 += g * q2.z; p3 += g * q3.z;
        g = gelu_fast((u.w + w.w) * rstd * lw.w + lb.w); p0 += g * q0.w; p1 += g * q1.w; p2 += g * q2.w; p3 += g * q3.w;
    }
    __half2 h01 = __floats2half2_rn(p0 + e2b[0], p1 + e2b[1]);
    __half2 h23 = __floats2half2_rn(p2 + e2b[2], p3 + e2b[3]);
    __half* dst = ew + ((size_t)(b * NN + i0 + ti) * NN + j0 + tj) * 4;
    *(__half2*)dst = h01;
    *(__half2*)(dst + 2) = h23;
}

// Aggregate per (b,i): softmax over j (NH heads, stats in registers) + AV
// (float4, exp-on-the-fly) + split-K o-proj + residual + LN.
template<int NH>
__global__ __launch_bounds__(256) void k_agg(
    const float* __restrict__ resid, const float* __restrict__ vbuf,
    const __half* __restrict__ sc,
    const float* __restrict__ ow, const float* __restrict__ ob,
    const float* __restrict__ nw, const float* __restrict__ nb,
    float* __restrict__ outp)
{
    constexpr int GL = 256 / NH;     // lanes per head group (32 or 64)
    constexpr int NE = NN / GL;      // elems per thread (18 or 9)
    const int bi = blockIdx.x;
    const int b = bi / NN, i = bi - b * NN;
    const int t = threadIdx.x;

    __shared__ float st_m[NH], st_i[NH];
    __shared__ float aggp[8][128];
    __shared__ float agg_s[128];
    __shared__ float op[2][128];
    __shared__ float red1[4], red2[4];

    const __half* srow = sc + (size_t)(b * NN + i) * NN * NH;

    // phase 1: per-head max & expsum, register-resident
    {
        const int h = t / GL, jl = t % GL;
        float sv[NE];
        #pragma unroll
        for (int k = 0; k < NE; ++k)
            sv[k] = __half2float(srow[(size_t)(jl + k * GL) * NH + h]);
        float mx = -1e30f;
        #pragma unroll
        for (int k = 0; k < NE; ++k) mx = fmaxf(mx, sv[k]);
        #pragma unroll
        for (int off = GL / 2; off > 0; off >>= 1) mx = fmaxf(mx, __shfl_xor(mx, off));
        float sm = 0.f;
        #pragma unroll
        for (int k = 0; k < NE; ++k) sm += __expf(sv[k] - mx);
        #pragma unroll
        for (int off = GL / 2; off > 0; off >>= 1) sm += __shfl_xor(sm, off);
        if (jl == 0) { st_m[h] = mx; st_i[h] = 1.0f / sm; }
    }
    __syncthreads();

    // phase 2: AV, thread = (jg, 4 channels)
    {
        const int c4 = (t & 31) * 4, jg = t >> 5;
        const int h2 = c4 >> ((NH == 8) ? 4 : 5);
        const float m2 = st_m[h2], inv2 = st_i[h2];
        float4 acc = {0.f, 0.f, 0.f, 0.f};
        const float* vb = vbuf + 256 + c4;
        #pragma unroll 4
        for (int j = jg; j < NN; j += 8) {
            float p = __expf(__half2float(srow[(size_t)j * NH + h2]) - m2);
            const float4 v4 = *(const float4*)(vb + (size_t)(b * NN + j) * 384);
            acc.x += p * v4.x; acc.y += p * v4.y; acc.z += p * v4.z; acc.w += p * v4.w;
        }
        acc.x *= inv2; acc.y *= inv2; acc.z *= inv2; acc.w *= inv2;
        *(float4*)&aggp[jg][c4] = acc;
    }
    __syncthreads();
    if (t < 128) {
        float s = 0.f;
        #pragma unroll
        for (int gq = 0; gq < 8; ++gq) s += aggp[gq][t];
        agg_s[t] = s;
    }
    __syncthreads();

    // phase 3: o-proj split-K over 2 halves
    {
        const int c = t & 127, half = t >> 7;
        float o = 0.f;
        const float4* wr = (const float4*)(ow + (size_t)c * 128 + half * 64);
        const float4* ar = (const float4*)(agg_s + half * 64);
        #pragma unroll
        for (int kq = 0; kq < 16; ++kq) {
            float4 w = wr[kq], a = ar[kq];
            o += w.x * a.x + w.y * a.y + w.z * a.z + w.w * a.w;
        }
        op[half][c] = o;
    }
    __syncthreads();
    float val = 0.f;
    if (t < 128)
        val = op[0][t] + op[1][t] + ob[t] + resid[(size_t)(b * NN + i) * 128 + t];

    // phase 4: LN
    float s1 = val, s2 = val * val;
    #pragma unroll
    for (int off = 32; off > 0; off >>= 1) {
        s1 += __shfl_xor(s1, off);
        s2 += __shfl_xor(s2, off);
    }
    if ((t & 63) == 0) { red1[t >> 6] = s1; red2[t >> 6] = s2; }
    __syncthreads();
    float tot1 = red1[0] + red1[1] + red1[2] + red1[3];
    float tot2 = red2[0] + red2[1] + red2[2] + red2[3];
    float mean = tot1 * (1.0f / 128.0f);
    float var = tot2 * (1.0f / 128.0f) - mean * mean;
    float rstd = rsqrtf(var + EPSV);
    if (t < 128)
        outp[(size_t)(b * NN + i) * 128 + t] = (val - mean) * rstd * nw[t] + nb[t];
}

// Final: LN(n2) on g, concat, f1 + LN + gelu + f2, + tokens, write (B,C,H,W)
__global__ __launch_bounds__(128) void k_final(
    const float* __restrict__ tok, const float* __restrict__ attn, const float* __restrict__ g,
    const float* __restrict__ n2w, const float* __restrict__ n2b,
    const float* __restrict__ f1w, const float* __restrict__ f1b,
    const float* __restrict__ flnw, const float* __restrict__ flnb,
    const float* __restrict__ f2w, const float* __restrict__ f2b,
    float* __restrict__ out)
{
    const int bi = blockIdx.x;
    const int b = bi / NN, i = bi - b * NN;
    const int t = threadIdx.x;
    __shared__ float cat_s[256];
    __shared__ float gl_s[128];
    __shared__ float red1[2], red2[2];

    const size_t row = (size_t)(b * NN + i) * 128;
    cat_s[t] = attn[row + t];
    float gv = g[row + t];
    {
        float s1 = gv, s2 = gv * gv;
        #pragma unroll
        for (int off = 32; off > 0; off >>= 1) { s1 += __shfl_xor(s1, off); s2 += __shfl_xor(s2, off); }
        if ((t & 63) == 0) { red1[t >> 6] = s1; red2[t >> 6] = s2; }
        __syncthreads();
        float mean = (red1[0] + red1[1]) * (1.0f / 128.0f);
        float var = (red2[0] + red2[1]) * (1.0f / 128.0f) - mean * mean;
        float rstd = rsqrtf(var + EPSV);
        cat_s[128 + t] = (gv - mean) * rstd * n2w[t] + n2b[t];
    }
    __syncthreads();
    float f = f1b[t];
    {
        const float4* wr = reinterpret_cast<const float4*>(f1w + (size_t)t * 256);
        const float4* cr = reinterpret_cast<const float4*>(cat_s);
        #pragma unroll 8
        for (int kq = 0; kq < 64; ++kq) {
            float4 w = wr[kq], c = cr[kq];
            f += w.x * c.x + w.y * c.y + w.z * c.z + w.w * c.w;
        }
    }
    {
        float s1 = f, s2 = f * f;
        #pragma unroll
        for (int off = 32; off > 0; off >>= 1) { s1 += __shfl_xor(s1, off); s2 += __shfl_xor(s2, off); }
        __syncthreads();
        if ((t & 63) == 0) { red1[t >> 6] = s1; red2[t >> 6] = s2; }
        __syncthreads();
        float mean = (red1[0] + red1[1]) * (1.0f / 128.0f);
        float var = (red2[0] + red2[1]) * (1.0f / 128.0f) - mean * mean;
        float rstd = rsqrtf(var + EPSV);
        float nrm = (f - mean) * rstd * flnw[t] + flnb[t];
        gl_s[t] = gelu_exact(nrm);
    }
    __syncthreads();
    float o = f2b[t];
    {
        const float4* wr = reinterpret_cast<const float4*>(f2w + (size_t)t * 128);
        const float4* gr = reinterpret_cast<const float4*>(gl_s);
        #pragma unroll 8
        for (int kq = 0; kq < 32; ++kq) {
            float4 w = wr[kq], gg = gr[kq];
            o += w.x * gg.x + w.y * gg.y + w.z * gg.z + w.w * gg.w;
        }
    }
    out[((size_t)b * 128 + t) * NN + i] = tok[row + t] + o;
}

extern "C" void kernel_launch(void* const* d_in, const int* in_sizes, int n_in,
                              void* d_out, int out_size, void* d_ws, size_t ws_size,
                              hipStream_t stream) {
    const float* x         = (const float*)d_in[0];
    const float* mha_in_b  = (const float*)d_in[2];
    const float* mha_out_w = (const float*)d_in[3];
    const float* mha_out_b = (const float*)d_in[4];
    const float* gv_w[2]  = {(const float*)d_in[5],  (const float*)d_in[17]};
    const float* gv_b[2]  = {(const float*)d_in[6],  (const float*)d_in[18]};
    const float* ge1_w[2] = {(const float*)d_in[7],  (const float*)d_in[19]};
    const float* ge1_b[2] = {(const float*)d_in[8],  (const float*)d_in[20]};
    const float* geln_w[2]= {(const float*)d_in[9],  (const float*)d_in[21]};
    const float* geln_b[2]= {(const float*)d_in[10], (const float*)d_in[22]};
    const float* ge2_w[2] = {(const float*)d_in[11], (const float*)d_in[23]};
    const float* ge2_b[2] = {(const float*)d_in[12], (const float*)d_in[24]};
    const float* go_w[2]  = {(const float*)d_in[13], (const float*)d_in[25]};
    const float* go_b[2]  = {(const float*)d_in[14], (const float*)d_in[26]};
    const float* gn_w[2]  = {(const float*)d_in[15], (const float*)d_in[27]};
    const float* gn_b[2]  = {(const float*)d_in[16], (const float*)d_in[28]};
    const float* n1w = (const float*)d_in[29];
    const float* n1b = (const float*)d_in[30];
    const float* n2w = (const float*)d_in[31];
    const float* n2b = (const float*)d_in[32];
    const float* f1w = (const float*)d_in[33];
    const float* f1b = (const float*)d_in[34];
    const float* flnw = (const float*)d_in[35];
    const float* flnb = (const float*)d_in[36];
    const float* f2w = (const float*)d_in[37];
    const float* f2b = (const float*)d_in[38];

    float* ws     = (float*)d_ws;
    float* tokens = ws;                       // 147456
    float* attn   = tokens + 147456;          // 147456
    float* g      = attn + 147456;            // 147456
    float* qkv    = g + 147456;               // 442368
    float* wTq    = qkv + 442368;             // 49152
    float* wT0    = wTq + 49152;              // 49152
    float* wT1    = wT0 + 49152;              // 49152
    // fp16 region: sc (MHA scores, [b][i][j][8]) aliases ewh ([b][i][j][4]) —
    // sc fully consumed by k_agg<8> before first k_edge write.
    __half* sc    = (__half*)(wT1 + 49152);   // 10.6 MB
    __half* ewh   = sc;

    k_tok<<<dim3(288, 2), 256, 0, stream>>>(x, tokens);
    k_prep<<<dim3(192, 3), 256, 0, stream>>>((const float*)d_in[1],
        ge1_w[0], gv_w[0], ge1_w[1], gv_w[1], wTq, wT0, wT1);

    k_gemmT<false><<<288, 384, 0, stream>>>(tokens, wTq,
        mha_in_b, mha_in_b + 128, mha_in_b + 256, qkv);
    k_score<<<dim3(36, 36, 2), 256, 0, stream>>>(qkv, sc);
    k_agg<8><<<1152, 256, 0, stream>>>(tokens, qkv, sc, mha_out_w, mha_out_b,
                                       n1w, n1b, attn);

    for (int l = 0; l < 2; ++l) {
        const float* xin = (l == 0) ? attn : g;
        const float* wTl = (l == 0) ? wT0 : wT1;
        k_gemmT<true><<<288, 384, 0, stream>>>(xin, wTl,
            nullptr, ge1_b[l], gv_b[l], qkv);
        k_edge<<<dim3(36, 36, 2), 256, 0, stream>>>(qkv, geln_w[l], geln_b[l],
                                                    ge2_w[l], ge2_b[l], ewh);
        k_agg<4><<<1152, 256, 0, stream>>>(xin, qkv, ewh, go_w[l], go_b[l],
                                           gn_w[l], gn_b[l], g);
    }
    k_final<<<1152, 128, 0, stream>>>(tokens, attn, g, n2w, n2b,
        f1w, f1b, flnw, flnb, f2w, f2b, (float*)d_out);
}

// Round 5
// 229.166 us; speedup vs baseline: 5.6715x; 1.3382x over previous
//
#include <hip/hip_runtime.h>
#include <hip/hip_fp16.h>
#include <math.h>

#define NN 576
#define EPSV 1e-5f

typedef _Float16 h2v __attribute__((ext_vector_type(2)));
__device__ __forceinline__ float fdot2f(__half2 a, __half2 b, float c) {
    return __builtin_amdgcn_fdot2(__builtin_bit_cast(h2v, a),
                                  __builtin_bit_cast(h2v, b), c, false);
}

__device__ __forceinline__ float gelu_exact(float x) {
    return 0.5f * x * (1.0f + erff(x * 0.70710678118654752f));
}

// x (B,C,HW) -> tokens (B,HW,C)
__global__ void k_tok(const float* __restrict__ x, float* __restrict__ tok) {
    int b = blockIdx.y;
    int idx = blockIdx.x * 256 + threadIdx.x;
    if (idx < NN * 128) {
        int n = idx >> 7, c = idx & 127;
        tok[(size_t)b * NN * 128 + idx] = x[((size_t)b * 128 + c) * NN + n];
    }
}

// y=0: wTq; y=1: wT0; y=2: wT1; y=3: pack half weights [lw|lb|e2w] per layer
__global__ void k_prep(const float* __restrict__ mha_in_w,
                       const float* __restrict__ e1w0, const float* __restrict__ vw0,
                       const float* __restrict__ e1w1, const float* __restrict__ vw1,
                       const float* __restrict__ lnw0, const float* __restrict__ lnb0,
                       const float* __restrict__ e2w0,
                       const float* __restrict__ lnw1, const float* __restrict__ lnb1,
                       const float* __restrict__ e2w1,
                       float* __restrict__ wTq, float* __restrict__ wT0,
                       float* __restrict__ wT1, __half* __restrict__ wh) {
    int which = blockIdx.y;
    int idx = blockIdx.x * 256 + threadIdx.x;   // 49152
    if (which == 3) {
        if (idx < 1536) {
            int l = idx / 768, i2 = idx - l * 768;
            const float* lw = l ? lnw1 : lnw0;
            const float* lb = l ? lnb1 : lnb0;
            const float* e2 = l ? e2w1 : e2w0;
            float v;
            if (i2 < 128)      v = lw[i2];
            else if (i2 < 256) v = lb[i2 - 128];
            else               v = e2[i2 - 256];
            wh[idx] = __float2half(v);
        }
        return;
    }
    int k = idx / 384, o = idx - k * 384;
    if (which == 0) {
        wTq[idx] = mha_in_w[o * 128 + k];
    } else {
        const float* e1w = (which == 1) ? e1w0 : e1w1;
        const float* vw  = (which == 1) ? vw0  : vw1;
        float v;
        if (o < 128)      v = e1w[o * 256 + k];
        else if (o < 256) v = e1w[(o - 128) * 256 + 128 + k];
        else              v = vw[(o - 256) * 128 + k];
        ((which == 1) ? wT0 : wT1)[idx] = v;
    }
}

// out row: chunks 0,1 written as HALF into the row's first 512B (fp16 copy for
// k_score/k_edge); chunk 2 (V) written fp32 at floats 256..383. Optional
// centering of chunks 0,1 (bias included).
template<bool CENTER>
__global__ __launch_bounds__(384) void k_gemmT(
    const float* __restrict__ A, const float* __restrict__ wT,
    const float* __restrict__ b0, const float* __restrict__ b1, const float* __restrict__ b2,
    float* __restrict__ out)
{
    const int t = threadIdx.x;
    const int r0 = blockIdx.x * 4;
    __shared__ float a_s[4][132];
    if (t < 128) {
        float4 v = *(const float4*)(A + (size_t)(r0 + (t >> 5)) * 128 + (t & 31) * 4);
        *(float4*)&a_s[t >> 5][(t & 31) * 4] = v;
    }
    __syncthreads();
    float acc[4] = {0.f, 0.f, 0.f, 0.f};
    #pragma unroll 8
    for (int k = 0; k < 128; ++k) {
        float w = wT[(size_t)k * 384 + t];
        acc[0] += a_s[0][k] * w;
        acc[1] += a_s[1][k] * w;
        acc[2] += a_s[2][k] * w;
        acc[3] += a_s[3][k] * w;
    }
    const float* bp = (t < 128) ? b0 : ((t < 256) ? b1 : b2);
    float bv = bp ? bp[t & 127] : 0.f;
    #pragma unroll
    for (int r = 0; r < 4; ++r) acc[r] += bv;

    if (CENTER) {
        __shared__ float redc[6][4];
        const int wv = t >> 6, ln = t & 63;
        #pragma unroll
        for (int r = 0; r < 4; ++r) {
            float xr = acc[r];
            #pragma unroll
            for (int off = 32; off > 0; off >>= 1) xr += __shfl_xor(xr, off);
            if (ln == 0) redc[wv][r] = xr;
        }
        __syncthreads();
        if (t < 256) {
            const int ch = t >> 7;
            #pragma unroll
            for (int r = 0; r < 4; ++r) {
                float mean = (redc[2 * ch][r] + redc[2 * ch + 1][r]) * (1.0f / 128.0f);
                acc[r] -= mean;
            }
        }
    }
    if (t < 256) {
        #pragma unroll
        for (int r = 0; r < 4; ++r)
            ((__half*)(out + (size_t)(r0 + r) * 384))[t] = __float2half(acc[r]);
    } else {
        #pragma unroll
        for (int r = 0; r < 4; ++r)
            out[(size_t)(r0 + r) * 384 + t] = acc[r];
    }
}

// MHA scores via fdot2 on half q|k: one thread per (i,j), 8 heads.
__global__ __launch_bounds__(256) void k_score(
    const float* __restrict__ qkv, __half* __restrict__ sc)
{
    const int jt = blockIdx.x, it = blockIdx.y, b = blockIdx.z;
    const int i0 = it * 16, j0 = jt * 16;
    const int t = threadIdx.x;
    __shared__ __half q_s[16][136], k_s[16][136];
    for (int idx = t; idx < 512; idx += 256) {
        int tile = idx >> 8, r = (idx >> 4) & 15, cq = idx & 15;
        const __half* src = (const __half*)(qkv + (size_t)(b * NN + (tile ? j0 : i0) + r) * 384)
                            + (tile ? 128 : 0) + cq * 8;
        __half* dst = tile ? &k_s[r][cq * 8] : &q_s[r][cq * 8];
        *(uint4*)dst = *(const uint4*)src;
    }
    __syncthreads();
    const int ti = t >> 4, tj = t & 15;
    const uint4* qr = (const uint4*)q_s[ti];
    const uint4* kr = (const uint4*)k_s[tj];
    float acc[8] = {0.f,0.f,0.f,0.f,0.f,0.f,0.f,0.f};
    #pragma unroll
    for (int sstep = 0; sstep < 16; ++sstep) {
        uint4 q4 = qr[sstep], k4 = kr[sstep];
        const __half2* qh = (const __half2*)&q4;
        const __half2* kh = (const __half2*)&k4;
        #pragma unroll
        for (int p = 0; p < 4; ++p)
            acc[sstep >> 1] = fdot2f(qh[p], kh[p], acc[sstep >> 1]);
    }
    __half2 h[4];
    #pragma unroll
    for (int p = 0; p < 4; ++p)
        h[p] = __floats2half2_rn(acc[2 * p] * 0.25f, acc[2 * p + 1] * 0.25f);
    *(uint4*)(sc + ((size_t)(b * NN + i0 + ti) * NN + j0 + tj) * 8) = *(uint4*)h;
}

// Edge MLP fp16: packed LN+sigmoid-gelu, fdot2 accumulation. 1 thread = 1 pair.
__global__ __launch_bounds__(256) void k_edge(
    const float* __restrict__ qkv, const __half* __restrict__ wh,
    const float* __restrict__ e2b, __half* __restrict__ ew)
{
    const int jt = blockIdx.x, it = blockIdx.y, b = blockIdx.z;
    const int i0 = it * 16, j0 = jt * 16;
    const int t = threadIdx.x;
    __shared__ __half ua_s[16][136], wb_s[16][136], wh_s[768];

    for (int idx = t; idx < 512; idx += 256) {
        int tile = idx >> 8, r = (idx >> 4) & 15, cq = idx & 15;
        const __half* src = (const __half*)(qkv + (size_t)(b * NN + (tile ? j0 : i0) + r) * 384)
                            + (tile ? 128 : 0) + cq * 8;
        __half* dst = tile ? &wb_s[r][cq * 8] : &ua_s[r][cq * 8];
        *(uint4*)dst = *(const uint4*)src;
    }
    if (t < 96) *(uint4*)&wh_s[t * 8] = *(const uint4*)&wh[t * 8];
    __syncthreads();

    const int ti = t >> 4, tj = t & 15;
    const uint4* uar = (const uint4*)ua_s[ti];
    const uint4* wbr = (const uint4*)wb_s[tj];

    float s2 = 0.f;
    #pragma unroll
    for (int sstep = 0; sstep < 16; ++sstep) {
        uint4 u4 = uar[sstep], w4 = wbr[sstep];
        const __half2* uh = (const __half2*)&u4;
        const __half2* whp = (const __half2*)&w4;
        #pragma unroll
        for (int p = 0; p < 4; ++p) {
            __half2 e = __hadd2(uh[p], whp[p]);
            s2 = fdot2f(e, e, s2);
        }
    }
    const float rstd = rsqrtf(s2 * (1.0f / 128.0f) + EPSV);
    const __half2 rh   = __float2half2_rn(rstd);
    const __half2 cexp = __float2half2_rn(-2.4554672f);   // -1.702/ln2
    const __half2 one2 = __float2half2_rn(1.0f);

    float p0 = 0.f, p1 = 0.f, p2 = 0.f, p3 = 0.f;
    #pragma unroll 4
    for (int sstep = 0; sstep < 16; ++sstep) {
        uint4 u4 = uar[sstep], w4 = wbr[sstep];
        uint4 lw4 = *(const uint4*)&wh_s[sstep * 8];
        uint4 lb4 = *(const uint4*)&wh_s[128 + sstep * 8];
        uint4 q04 = *(const uint4*)&wh_s[256 + sstep * 8];
        uint4 q14 = *(const uint4*)&wh_s[384 + sstep * 8];
        uint4 q24 = *(const uint4*)&wh_s[512 + sstep * 8];
        uint4 q34 = *(const uint4*)&wh_s[640 + sstep * 8];
        const __half2* uh  = (const __half2*)&u4;
        const __half2* whp = (const __half2*)&w4;
        const __half2* lwh = (const __half2*)&lw4;
        const __half2* lbh = (const __half2*)&lb4;
        const __half2* q0h = (const __half2*)&q04;
        const __half2* q1h = (const __half2*)&q14;
        const __half2* q2h = (const __half2*)&q24;
        const __half2* q3h = (const __half2*)&q34;
        #pragma unroll
        for (int p = 0; p < 4; ++p) {
            __half2 e   = __hadd2(uh[p], whp[p]);
            __half2 rlw = __hmul2(rh, lwh[p]);
            __half2 nrm = __hfma2(e, rlw, lbh[p]);
            __half2 z   = __hmul2(nrm, cexp);
            __half2 ex  = h2exp2(z);
            __half2 den = __hadd2(ex, one2);
            __half2 rr  = h2rcp(den);
            __half2 g   = __hmul2(nrm, rr);      // x * sigmoid(1.702x)
            p0 = fdot2f(g, q0h[p], p0);
            p1 = fdot2f(g, q1h[p], p1);
            p2 = fdot2f(g, q2h[p], p2);
            p3 = fdot2f(g, q3h[p], p3);
        }
    }
    __half2 h01 = __floats2half2_rn(p0 + e2b[0], p1 + e2b[1]);
    __half2 h23 = __floats2half2_rn(p2 + e2b[2], p3 + e2b[3]);
    __half* dst = ew + ((size_t)(b * NN + i0 + ti) * NN + j0 + tj) * 4;
    *(__half2*)dst = h01;
    *(__half2*)(dst + 2) = h23;
}

// Aggregate per (b,i): softmax (register stats) + AV + split-K o-proj + LN.
template<int NH>
__global__ __launch_bounds__(256) void k_agg(
    const float* __restrict__ resid, const float* __restrict__ vbuf,
    const __half* __restrict__ sc,
    const float* __restrict__ ow, const float* __restrict__ ob,
    const float* __restrict__ nw, const float* __restrict__ nb,
    float* __restrict__ outp)
{
    constexpr int GL = 256 / NH;
    constexpr int NE = NN / GL;
    const int bi = blockIdx.x;
    const int b = bi / NN, i = bi - b * NN;
    const int t = threadIdx.x;

    __shared__ float st_m[NH], st_i[NH];
    __shared__ float aggp[8][128];
    __shared__ float agg_s[128];
    __shared__ float op[2][128];
    __shared__ float red1[4], red2[4];

    const __half* srow = sc + (size_t)(b * NN + i) * NN * NH;

    {
        const int h = t / GL, jl = t % GL;
        float sv[NE];
        #pragma unroll
        for (int k = 0; k < NE; ++k)
            sv[k] = __half2float(srow[(size_t)(jl + k * GL) * NH + h]);
        float mx = -1e30f;
        #pragma unroll
        for (int k = 0; k < NE; ++k) mx = fmaxf(mx, sv[k]);
        #pragma unroll
        for (int off = GL / 2; off > 0; off >>= 1) mx = fmaxf(mx, __shfl_xor(mx, off));
        float sm = 0.f;
        #pragma unroll
        for (int k = 0; k < NE; ++k) sm += __expf(sv[k] - mx);
        #pragma unroll
        for (int off = GL / 2; off > 0; off >>= 1) sm += __shfl_xor(sm, off);
        if (jl == 0) { st_m[h] = mx; st_i[h] = 1.0f / sm; }
    }
    __syncthreads();

    {
        const int c4 = (t & 31) * 4, jg = t >> 5;
        const int h2 = c4 >> ((NH == 8) ? 4 : 5);
        const float m2 = st_m[h2], inv2 = st_i[h2];
        float4 acc = {0.f, 0.f, 0.f, 0.f};
        const float* vb = vbuf + 256 + c4;
        #pragma unroll 4
        for (int j = jg; j < NN; j += 8) {
            float p = __expf(__half2float(srow[(size_t)j * NH + h2]) - m2);
            const float4 v4 = *(const float4*)(vb + (size_t)(b * NN + j) * 384);
            acc.x += p * v4.x; acc.y += p * v4.y; acc.z += p * v4.z; acc.w += p * v4.w;
        }
        acc.x *= inv2; acc.y *= inv2; acc.z *= inv2; acc.w *= inv2;
        *(float4*)&aggp[jg][c4] = acc;
    }
    __syncthreads();
    if (t < 128) {
        float s = 0.f;
        #pragma unroll
        for (int gq = 0; gq < 8; ++gq) s += aggp[gq][t];
        agg_s[t] = s;
    }
    __syncthreads();

    {
        const int c = t & 127, half = t >> 7;
        float o = 0.f;
        const float4* wr = (const float4*)(ow + (size_t)c * 128 + half * 64);
        const float4* ar = (const float4*)(agg_s + half * 64);
        #pragma unroll
        for (int kq = 0; kq < 16; ++kq) {
            float4 w = wr[kq], a = ar[kq];
            o += w.x * a.x + w.y * a.y + w.z * a.z + w.w * a.w;
        }
        op[half][c] = o;
    }
    __syncthreads();
    float val = 0.f;
    if (t < 128)
        val = op[0][t] + op[1][t] + ob[t] + resid[(size_t)(b * NN + i) * 128 + t];

    float s1 = val, s2 = val * val;
    #pragma unroll
    for (int off = 32; off > 0; off >>= 1) {
        s1 += __shfl_xor(s1, off);
        s2 += __shfl_xor(s2, off);
    }
    if ((t & 63) == 0) { red1[t >> 6] = s1; red2[t >> 6] = s2; }
    __syncthreads();
    float tot1 = red1[0] + red1[1] + red1[2] + red1[3];
    float tot2 = red2[0] + red2[1] + red2[2] + red2[3];
    float mean = tot1 * (1.0f / 128.0f);
    float var = tot2 * (1.0f / 128.0f) - mean * mean;
    float rstd = rsqrtf(var + EPSV);
    if (t < 128)
        outp[(size_t)(b * NN + i) * 128 + t] = (val - mean) * rstd * nw[t] + nb[t];
}

// Final: LN(n2) on g, concat, f1 + LN + gelu + f2, + tokens, write (B,C,H,W)
__global__ __launch_bounds__(128) void k_final(
    const float* __restrict__ tok, const float* __restrict__ attn, const float* __restrict__ g,
    const float* __restrict__ n2w, const float* __restrict__ n2b,
    const float* __restrict__ f1w, const float* __restrict__ f1b,
    const float* __restrict__ flnw, const float* __restrict__ flnb,
    const float* __restrict__ f2w, const float* __restrict__ f2b,
    float* __restrict__ out)
{
    const int bi = blockIdx.x;
    const int b = bi / NN, i = bi - b * NN;
    const int t = threadIdx.x;
    __shared__ float cat_s[256];
    __shared__ float gl_s[128];
    __shared__ float red1[2], red2[2];

    const size_t row = (size_t)(b * NN + i) * 128;
    cat_s[t] = attn[row + t];
    float gv = g[row + t];
    {
        float s1 = gv, s2 = gv * gv;
        #pragma unroll
        for (int off = 32; off > 0; off >>= 1) { s1 += __shfl_xor(s1, off); s2 += __shfl_xor(s2, off); }
        if ((t & 63) == 0) { red1[t >> 6] = s1; red2[t >> 6] = s2; }
        __syncthreads();
        float mean = (red1[0] + red1[1]) * (1.0f / 128.0f);
        float var = (red2[0] + red2[1]) * (1.0f / 128.0f) - mean * mean;
        float rstd = rsqrtf(var + EPSV);
        cat_s[128 + t] = (gv - mean) * rstd * n2w[t] + n2b[t];
    }
    __syncthreads();
    float f = f1b[t];
    {
        const float4* wr = reinterpret_cast<const float4*>(f1w + (size_t)t * 256);
        const float4* cr = reinterpret_cast<const float4*>(cat_s);
        #pragma unroll 8
        for (int kq = 0; kq < 64; ++kq) {
            float4 w = wr[kq], c = cr[kq];
            f += w.x * c.x + w.y * c.y + w.z * c.z + w.w * c.w;
        }
    }
    {
        float s1 = f, s2 = f * f;
        #pragma unroll
        for (int off = 32; off > 0; off >>= 1) { s1 += __shfl_xor(s1, off); s2 += __shfl_xor(s2, off); }
        __syncthreads();
        if ((t & 63) == 0) { red1[t >> 6] = s1; red2[t >> 6] = s2; }
        __syncthreads();
        float mean = (red1[0] + red1[1]) * (1.0f / 128.0f);
        float var = (red2[0] + red2[1]) * (1.0f / 128.0f) - mean * mean;
        float rstd = rsqrtf(var + EPSV);
        float nrm = (f - mean) * rstd * flnw[t] + flnb[t];
        gl_s[t] = gelu_exact(nrm);
    }
    __syncthreads();
    float o = f2b[t];
    {
        const float4* wr = reinterpret_cast<const float4*>(f2w + (size_t)t * 128);
        const float4* gr = reinterpret_cast<const float4*>(gl_s);
        #pragma unroll 8
        for (int kq = 0; kq < 32; ++kq) {
            float4 w = wr[kq], gg = gr[kq];
            o += w.x * gg.x + w.y * gg.y + w.z * gg.z + w.w * gg.w;
        }
    }
    out[((size_t)b * 128 + t) * NN + i] = tok[row + t] + o;
}

extern "C" void kernel_launch(void* const* d_in, const int* in_sizes, int n_in,
                              void* d_out, int out_size, void* d_ws, size_t ws_size,
                              hipStream_t stream) {
    const float* x         = (const float*)d_in[0];
    const float* mha_in_b  = (const float*)d_in[2];
    const float* mha_out_w = (const float*)d_in[3];
    const float* mha_out_b = (const float*)d_in[4];
    const float* gv_w[2]  = {(const float*)d_in[5],  (const float*)d_in[17]};
    const float* gv_b[2]  = {(const float*)d_in[6],  (const float*)d_in[18]};
    const float* ge1_w[2] = {(const float*)d_in[7],  (const float*)d_in[19]};
    const float* ge1_b[2] = {(const float*)d_in[8],  (const float*)d_in[20]};
    const float* geln_w[2]= {(const float*)d_in[9],  (const float*)d_in[21]};
    const float* geln_b[2]= {(const float*)d_in[10], (const float*)d_in[22]};
    const float* ge2_w[2] = {(const float*)d_in[11], (const float*)d_in[23]};
    const float* ge2_b[2] = {(const float*)d_in[12], (const float*)d_in[24]};
    const float* go_w[2]  = {(const float*)d_in[13], (const float*)d_in[25]};
    const float* go_b[2]  = {(const float*)d_in[14], (const float*)d_in[26]};
    const float* gn_w[2]  = {(const float*)d_in[15], (const float*)d_in[27]};
    const float* gn_b[2]  = {(const float*)d_in[16], (const float*)d_in[28]};
    const float* n1w = (const float*)d_in[29];
    const float* n1b = (const float*)d_in[30];
    const float* n2w = (const float*)d_in[31];
    const float* n2b = (const float*)d_in[32];
    const float* f1w = (const float*)d_in[33];
    const float* f1b = (const float*)d_in[34];
    const float* flnw = (const float*)d_in[35];
    const float* flnb = (const float*)d_in[36];
    const float* f2w = (const float*)d_in[37];
    const float* f2b = (const float*)d_in[38];

    float* ws     = (float*)d_ws;
    float* tokens = ws;                       // 147456
    float* attn   = tokens + 147456;          // 147456
    float* g      = attn + 147456;            // 147456
    float* qkv    = g + 147456;               // 442368 (fp32 V + embedded fp16 q|k / ua|wb)
    float* wTq    = qkv + 442368;             // 49152
    float* wT0    = wTq + 49152;              // 49152
    float* wT1    = wT0 + 49152;              // 49152
    __half* wh    = (__half*)(wT1 + 49152);   // 1536 (+pad to 2048)
    // fp16 region: sc (MHA scores [b][i][j][8]) aliases ewh ([b][i][j][4])
    __half* sc    = wh + 2048;                // 10.6 MB
    __half* ewh   = sc;

    k_tok<<<dim3(288, 2), 256, 0, stream>>>(x, tokens);
    k_prep<<<dim3(192, 4), 256, 0, stream>>>((const float*)d_in[1],
        ge1_w[0], gv_w[0], ge1_w[1], gv_w[1],
        geln_w[0], geln_b[0], ge2_w[0],
        geln_w[1], geln_b[1], ge2_w[1],
        wTq, wT0, wT1, wh);

    k_gemmT<false><<<288, 384, 0, stream>>>(tokens, wTq,
        mha_in_b, mha_in_b + 128, mha_in_b + 256, qkv);
    k_score<<<dim3(36, 36, 2), 256, 0, stream>>>(qkv, sc);
    k_agg<8><<<1152, 256, 0, stream>>>(tokens, qkv, sc, mha_out_w, mha_out_b,
                                       n1w, n1b, attn);

    for (int l = 0; l < 2; ++l) {
        const float* xin = (l == 0) ? attn : g;
        const float* wTl = (l == 0) ? wT0 : wT1;
        k_gemmT<true><<<288, 384, 0, stream>>>(xin, wTl,
            nullptr, ge1_b[l], gv_b[l], qkv);
        k_edge<<<dim3(36, 36, 2), 256, 0, stream>>>(qkv, wh + l * 768,
                                                    ge2_b[l], ewh);
        k_agg<4><<<1152, 256, 0, stream>>>(xin, qkv, ewh, go_w[l], go_b[l],
                                           gn_w[l], gn_b[l], g);
    }
    k_final<<<1152, 128, 0, stream>>>(tokens, attn, g, n2w, n2b,
        f1w, f1b, flnw, flnb, f2w, f2b, (float*)d_out);
}